// Round 13
// baseline (1656.533 us; speedup 1.0000x reference)
//
#include <hip/hip_runtime.h>
#include <hip/hip_bf16.h>

#define Bsz 4
#define Ssz 2048
#define Dsz 512
#define Hsz 8
#define Lsz 6
#define Vsz 8000
#define FFsz 2048
#define Msz (Bsz*Ssz)
#define VszPad 8192

typedef unsigned short u16;
typedef unsigned int u32;
typedef __attribute__((ext_vector_type(8))) short bf16x8;
typedef __attribute__((ext_vector_type(4))) float f32x4;
typedef __attribute__((ext_vector_type(16))) float f32x16;
typedef __attribute__((ext_vector_type(4))) u32 u32x4;
typedef __attribute__((ext_vector_type(4))) u16 u16x4;

__device__ __forceinline__ u16 f2b(float f) {
    union { float f; unsigned u; } x; x.f = f;
    return (u16)((x.u + 0x7fffu + ((x.u >> 16) & 1u)) >> 16);
}
__device__ __forceinline__ u16 f2bn(float f) {
    __hip_bfloat16 h = __float2bfloat16(f);
    return __builtin_bit_cast(u16, h);
}
__device__ __forceinline__ float b2f(u16 v) {
    union { u32 u; float f; } x; x.u = ((u32)v) << 16; return x.f;
}

#define GLOAD_LDS16(g, l) __builtin_amdgcn_global_load_lds( \
    (const __attribute__((address_space(1))) u32*)(g), \
    (__attribute__((address_space(3))) u32*)(l), 16, 0, 0)

// ---------------- embedding + positional encoding (bf16 out) ----------------
__global__ __launch_bounds__(256) void embed_kernel(const int* __restrict__ tokens,
                                                    const float* __restrict__ embed,
                                                    u16* __restrict__ x) {
    int idx = blockIdx.x * 256 + threadIdx.x;
    int row = idx >> 8, p = idx & 255;
    int tok = tokens[row];
    int s = row & (Ssz - 1);
    float div = __expf((float)p * (-9.210340371976184f / 256.f));
    float ang = (float)s * div;
    float2 e = ((const float2*)(embed + (size_t)tok * Dsz))[p];
    u32 o = (u32)f2b(e.x + sinf(ang)) | ((u32)f2b(e.y + cosf(ang)) << 16);
    ((u32*)(x + (size_t)row * Dsz))[p] = o;
}

// ---------------- layernorm (bf16 in -> bf16 out), 1 wave per row ----------------
__global__ __launch_bounds__(256) void ln_kernel(const u16* __restrict__ x,
                                                 const float* __restrict__ g,
                                                 const float* __restrict__ bta,
                                                 u16* __restrict__ out) {
    int wave = threadIdx.x >> 6, lane = threadIdx.x & 63;
    int row = blockIdx.x * 4 + wave;
    bf16x8 a = ((const bf16x8*)(x + (size_t)row * Dsz))[lane];
    float vals[8];
    #pragma unroll
    for (int i = 0; i < 8; ++i) vals[i] = b2f((u16)a[i]);
    float s = 0.f;
    #pragma unroll
    for (int i = 0; i < 8; ++i) s += vals[i];
    #pragma unroll
    for (int o = 32; o; o >>= 1) s += __shfl_xor(s, o);
    float mean = s * (1.f / 512.f);
    float sq = 0.f;
    #pragma unroll
    for (int i = 0; i < 8; ++i) { float d = vals[i] - mean; sq += d * d; }
    #pragma unroll
    for (int o = 32; o; o >>= 1) sq += __shfl_xor(sq, o);
    float rstd = rsqrtf(sq * (1.f / 512.f) + 1e-5f);
    int base = lane * 8;
    bf16x8 rv;
    #pragma unroll
    for (int i = 0; i < 8; ++i)
        rv[i] = (short)f2b((vals[i] - mean) * rstd * g[base + i] + bta[base + i]);
    *(bf16x8*)(out + (size_t)row * Dsz + base) = rv;
}

// ---------------- tiled transpose + fp32->bf16 convert ----------------
__global__ __launch_bounds__(256) void tconv_kernel(const float* __restrict__ src,
                                                    u16* __restrict__ dst,
                                                    int R, int C,
                                                    size_t sstride, size_t dstride) {
    __shared__ float tile[32][33];
    const float* s = src + blockIdx.z * sstride;
    u16* d = dst + blockIdx.z * dstride;
    int c0 = blockIdx.x * 32, r0 = blockIdx.y * 32;
    int tx = threadIdx.x & 31, ty = threadIdx.x >> 5;
    #pragma unroll
    for (int i = 0; i < 32; i += 8)
        tile[ty + i][tx] = s[(size_t)(r0 + ty + i) * C + c0 + tx];
    __syncthreads();
    #pragma unroll
    for (int i = 0; i < 32; i += 8)
        d[(size_t)(c0 + ty + i) * R + r0 + tx] = f2b(tile[tx][ty + i]);
}

// ---------------- merged wq/wk/wv transpose ----------------
__global__ __launch_bounds__(256) void tconvqkv_kernel(const float* __restrict__ wq,
                                                       const float* __restrict__ wk,
                                                       const float* __restrict__ wv,
                                                       u16* __restrict__ dst) {
    __shared__ float tile[32][33];
    int z = blockIdx.z, which = z / Lsz, l = z % Lsz;
    const float* s = (which == 0 ? wq : which == 1 ? wk : wv) + (size_t)l * Dsz * Dsz;
    u16* d = dst + ((size_t)l * 3 + which) * Dsz * Dsz;
    int c0 = blockIdx.x * 32, r0 = blockIdx.y * 32;
    int tx = threadIdx.x & 31, ty = threadIdx.x >> 5;
    #pragma unroll
    for (int i = 0; i < 32; i += 8)
        tile[ty + i][tx] = s[(size_t)(r0 + ty + i) * Dsz + c0 + tx];
    __syncthreads();
    #pragma unroll
    for (int i = 0; i < 32; i += 8)
        d[(size_t)(c0 + ty + i) * Dsz + r0 + tx] = f2b(tile[tx][ty + i]);
}

// ---------------- legacy 2-barrier GEMM (proven): used for wo/ffn2 (N=512, BMF=2) ----------------
template<bool BIAS, bool RES, bool RELU, bool OF32, bool OBF16, bool XN, int BMF, bool QKV>
__global__ __launch_bounds__(256, 4) void gemm_kernel(const u16* __restrict__ A,
                                                   const u16* __restrict__ BT,
                                                   const float* __restrict__ bias,
                                                   const u16* __restrict__ res,
                                                   float* __restrict__ outf,
                                                   u16* __restrict__ outb,
                                                   u16* __restrict__ vT,
                                                   int M, int N, int K) {
    __shared__ u16 As[BMF * 32 * 64];
    __shared__ u16 Bs[128 * 64];
    int tid = threadIdx.x;
    int wave = tid >> 6, lane = tid & 63;
    int wm = wave >> 1, wn = wave & 1;
    int gx = gridDim.x;
    int bid = blockIdx.y * gx + blockIdx.x;
    int xcd = bid & 7, j = bid >> 3;
    int mblk, nblk;
    if (XN) { mblk = j >> 3; nblk = xcd * 8 + (j & 7); }
    else    { int sm = gridDim.y >> 3; mblk = xcd * sm + j / gx; nblk = j % gx; }
    int m0 = mblk * (BMF * 32), n0 = nblk * 128;
    int lr = lane & 15, lg = lane >> 4;
    int srow = lane >> 3;
    int scol = (lane & 7) * 8;
    f32x4 acc[BMF][4] = {};
    for (int k0 = 0; k0 < K; k0 += 64) {
        #pragma unroll
        for (int i = 0; i < BMF; ++i) {
            int chunk = wave * BMF + i;
            int r = chunk * 8 + srow;
            GLOAD_LDS16(A + (size_t)(m0 + r) * K + k0 + scol, &As[chunk * 512]);
        }
        #pragma unroll
        for (int i = 0; i < 4; ++i) {
            int chunk = wave * 4 + i;
            int r = chunk * 8 + srow;
            GLOAD_LDS16(BT + (size_t)(n0 + r) * K + k0 + scol, &Bs[chunk * 512]);
        }
        __syncthreads();
        #pragma unroll
        for (int kk = 0; kk < 2; ++kk) {
            bf16x8 af[BMF], bfr[4];
            #pragma unroll
            for (int m = 0; m < BMF; ++m)
                af[m] = *(const bf16x8*)(As + (wm * (BMF * 16) + m * 16 + lr) * 64 + kk * 32 + lg * 8);
            #pragma unroll
            for (int n = 0; n < 4; ++n)
                bfr[n] = *(const bf16x8*)(Bs + (wn * 64 + n * 16 + lr) * 64 + kk * 32 + lg * 8);
            #pragma unroll
            for (int m = 0; m < BMF; ++m)
                #pragma unroll
                for (int n = 0; n < 4; ++n)
                    acc[m][n] = __builtin_amdgcn_mfma_f32_16x16x32_bf16(af[m], bfr[n], acc[m][n], 0, 0, 0);
        }
        __syncthreads();
    }
    #pragma unroll
    for (int m = 0; m < BMF; ++m) {
        int row = m0 + wm * (BMF * 16) + m * 16 + lg * 4;
        #pragma unroll
        for (int n = 0; n < 4; ++n) {
            int col = n0 + wn * 64 + n * 16 + lr;
            if (col < N) {
                float bv = BIAS ? bias[col] : 0.f;
                #pragma unroll
                for (int j2 = 0; j2 < 4; ++j2) {
                    float v = acc[m][n][j2] + bv;
                    if (RES) v += b2f(res[(size_t)(row + j2) * N + col]);
                    if (RELU) v = fmaxf(v, 0.f);
                    if (OF32) outf[(size_t)(row + j2) * N + col] = v;
                    if (OBF16) outb[(size_t)(row + j2) * N + col] = f2b(v);
                }
            }
        }
    }
}

// ---------------- gemmP: counted-vmcnt pipelined GEMM (T3/T4 + T2 swizzle) ----------------
// 256x128 tile, 512 thr / 8 waves (4M x 2N), BK=64, ring-3 LDS (144KB), depth-2 prefetch.
// Per iter: issue tile t+2 (6 gload_lds) -> swizzled ds_read + 32 MFMA -> {vmcnt(6); s_barrier}
// in ONE memory-clobbered asm (no IR pass can slide a read between wait and barrier).
// vmcnt(6) leaves only tile t+2's 6 loads outstanding => tile t+1 fully landed. Ring slot
// (t+2)%3 == (t-1)%3 was consumed (lgkmcnt before MFMA) before the t-1 end barrier. Safe.
// LDS swizzle (both-sides): stage global col16 = (lane&7)^(lane>>3); read slot = (kk*4+lg)^(lr&7).
template<bool BIAS, bool RELU, bool OF32, bool OBF16, bool XN, bool QKV>
__global__ __launch_bounds__(512, 1) void gemmP_kernel(const u16* __restrict__ A,
                                                       const u16* __restrict__ BT,
                                                       const float* __restrict__ bias,
                                                       float* __restrict__ outf,
                                                       u16* __restrict__ outb,
                                                       u16* __restrict__ vT,
                                                       int M, int N, int K) {
    __shared__ u16 As[3][256 * 64];
    __shared__ u16 Bs[3][128 * 64];
    int tid = threadIdx.x;
    int wave = tid >> 6, lane = tid & 63;
    int wm = wave >> 1, wn = wave & 1;          // 4M x 2N wave grid
    int gx = gridDim.x;
    int bid = blockIdx.y * gx + blockIdx.x;
    int xcd = bid & 7, j = bid >> 3;
    int mblk, nblk;
    if (XN) { int npx = gx >> 3; nblk = xcd * npx + (j % npx); mblk = j / npx; }
    else    { int sm = gridDim.y >> 3; mblk = xcd * sm + j / gx; nblk = j % gx; }
    int m0 = mblk * 256, n0 = nblk * 128;
    int lr = lane & 15, lg = lane >> 4;
    int sr8 = lane >> 3;                        // 0..7 staging row-in-8
    int gc16 = ((lane & 7) ^ sr8) * 8;          // pre-swizzled global col (elements)
    int nt = K >> 6;

    auto issue = [&](int t) {
        int rg = t % 3;
        int k0 = t << 6;
        #pragma unroll
        for (int i = 0; i < 4; ++i)             // A: 256 rows
            GLOAD_LDS16(A + (size_t)(m0 + i * 64 + wave * 8 + sr8) * K + k0 + gc16,
                        &As[rg][i * 4096 + wave * 512]);
        #pragma unroll
        for (int i = 0; i < 2; ++i)             // B: 128 rows
            GLOAD_LDS16(BT + (size_t)(n0 + i * 64 + wave * 8 + sr8) * K + k0 + gc16,
                        &Bs[rg][i * 4096 + wave * 512]);
    };

    f32x4 acc[4][4] = {};
    issue(0); issue(1);
    __builtin_amdgcn_sched_barrier(0);
    asm volatile("s_waitcnt vmcnt(6)\n\ts_barrier" ::: "memory");  // tile 0 landed, collective
    __builtin_amdgcn_sched_barrier(0);

    for (int t = 0; t < nt; ++t) {
        if (t + 2 < nt) issue(t + 2);
        const u16* Ar = As[t % 3];
        const u16* Br = Bs[t % 3];
        #pragma unroll
        for (int kk = 0; kk < 2; ++kk) {
            bf16x8 af[4], bfr[4];
            #pragma unroll
            for (int m = 0; m < 4; ++m) {
                int r = wm * 64 + m * 16 + lr;
                int slot = (kk * 4 + lg) ^ (lr & 7);
                af[m] = *(const bf16x8*)((const char*)Ar + r * 128 + slot * 16);
            }
            #pragma unroll
            for (int n = 0; n < 4; ++n) {
                int r = wn * 64 + n * 16 + lr;
                int slot = (kk * 4 + lg) ^ (lr & 7);
                bfr[n] = *(const bf16x8*)((const char*)Br + r * 128 + slot * 16);
            }
            #pragma unroll
            for (int m = 0; m < 4; ++m)
                #pragma unroll
                for (int n = 0; n < 4; ++n)
                    acc[m][n] = __builtin_amdgcn_mfma_f32_16x16x32_bf16(af[m], bfr[n], acc[m][n], 0, 0, 0);
        }
        __builtin_amdgcn_sched_barrier(0);
        if (t + 2 < nt) asm volatile("s_waitcnt vmcnt(6)\n\ts_barrier" ::: "memory");  // t+1 landed
        else            asm volatile("s_waitcnt vmcnt(0)\n\ts_barrier" ::: "memory");  // tail drain
        __builtin_amdgcn_sched_barrier(0);
    }

    #pragma unroll
    for (int m = 0; m < 4; ++m) {
        int row = m0 + wm * 64 + m * 16 + lg * 4;
        #pragma unroll
        for (int n = 0; n < 4; ++n) {
            int col = n0 + wn * 64 + n * 16 + lr;
            if (QKV && col >= 1024) {
                int hd = col - 1024;
                int hh = hd >> 6; hd &= 63;
                int b = row >> 11, s = row & 2047;
                u16x4 v4;
                #pragma unroll
                for (int j2 = 0; j2 < 4; ++j2) v4[j2] = f2b(acc[m][n][j2]);
                *(u16x4*)(vT + ((size_t)(b * 8 + hh) * 64 + hd) * Ssz + s) = v4;
            } else if (col < N) {
                float bv = BIAS ? bias[col] : 0.f;
                #pragma unroll
                for (int j2 = 0; j2 < 4; ++j2) {
                    float v = acc[m][n][j2] + bv;
                    if (RELU) v = fmaxf(v, 0.f);
                    if (OF32) outf[(size_t)(row + j2) * N + col] = v;
                    if (OBF16) outb[(size_t)(row + j2) * N + col] = f2b(v);
                }
            }
        }
    }
}

// ---------------- flash attention v5: double-buffered K/V + async-stage, 1 barrier/tile ----------------
__global__ __launch_bounds__(256, 2) void flash5_kernel(const u16* __restrict__ qkv,
                                                        const u16* __restrict__ vT,
                                                        u16* __restrict__ o) {
    __shared__ u16 Ks[2][64 * 64];
    __shared__ u16 Vs[2][64 * 64];
    int blk = blockIdx.x;
    int bh = blk & 31;
    int c = 15 - (blk >> 5);
    int b = bh >> 3, hh = bh & 7;
    int tid = threadIdx.x, wave = tid >> 6, lane = tid & 63;
    int l31 = lane & 31, h5 = lane >> 5;
    int g = c * 4 + wave;
    int qg = g * 32 + l31;
    int ext = (g >> 1) + 1;
    int nt = 2 * c + 2;
    const float cs = 0.044194173824159216f;

    bf16x8 qf[4];
    {
        const u16* qrow = qkv + (size_t)(b * Ssz + qg) * 1536 + hh * 64;
        #pragma unroll
        for (int cb = 0; cb < 4; ++cb)
            qf[cb] = *(const bf16x8*)(qrow + cb * 16 + h5 * 8);
    }
    f32x16 Oa0 = {}, Oa1 = {};
    float m_run = -1e30f, l_run = 0.f;
    int sr = tid >> 3;
    int sc2 = (tid & 7) * 8;
    const u16* kbase = qkv + (size_t)(b * Ssz) * 1536 + 512 + hh * 64;
    const u16* vbase = vT + (size_t)bh * 64 * Ssz;
    int byteA = (sr * 128 + sc2 * 2) ^ ((sr & 7) << 4);
    int byteB = ((sr + 32) * 128 + sc2 * 2) ^ ((sr & 7) << 4);

    {
        bf16x8 kA = *(const bf16x8*)(kbase + (size_t)sr * 1536 + sc2);
        bf16x8 kB = *(const bf16x8*)(kbase + (size_t)(32 + sr) * 1536 + sc2);
        bf16x8 vA = *(const bf16x8*)(vbase + (size_t)sr * Ssz + sc2);
        bf16x8 vB = *(const bf16x8*)(vbase + (size_t)(32 + sr) * Ssz + sc2);
        *(bf16x8*)((char*)Ks[0] + byteA) = kA;
        *(bf16x8*)((char*)Ks[0] + byteB) = kB;
        *(bf16x8*)((char*)Vs[0] + byteA) = vA;
        *(bf16x8*)((char*)Vs[0] + byteB) = vB;
    }
    __syncthreads();

    for (int kt = 0; kt < nt; ++kt) {
        int cur = kt & 1;
        bool pf = (kt + 1 < nt);
        bf16x8 kA, kB, vA, vB;
        if (pf) {
            kA = *(const bf16x8*)(kbase + (size_t)((kt + 1) * 64 + sr) * 1536 + sc2);
            kB = *(const bf16x8*)(kbase + (size_t)((kt + 1) * 64 + 32 + sr) * 1536 + sc2);
            vA = *(const bf16x8*)(vbase + (size_t)sr * Ssz + (kt + 1) * 64 + sc2);
            vB = *(const bf16x8*)(vbase + (size_t)(32 + sr) * Ssz + (kt + 1) * 64 + sc2);
        }
        const u16* Kc = Ks[cur];
        const u16* Vc = Vs[cur];
        if (kt < ext) {
            bool dtile = (kt == ext - 1);
            int mts = (dtile && !(g & 1)) ? 1 : 2;
            f32x16 st[2] = {};
            __builtin_amdgcn_s_setprio(1);
            #pragma unroll
            for (int mt = 0; mt < 2; ++mt)
                if (mt < mts) {
                    int r = mt * 32 + l31;
                    #pragma unroll
                    for (int cb = 0; cb < 4; ++cb) {
                        int byte = (r * 128 + (cb * 16 + h5 * 8) * 2) ^ ((r & 7) << 4);
                        bf16x8 kf = *(const bf16x8*)((char*)Kc + byte);
                        st[mt] = __builtin_amdgcn_mfma_f32_32x32x16_bf16(kf, qf[cb], st[mt], 0, 0, 0);
                    }
                }
            __builtin_amdgcn_s_setprio(0);
            float pmax = -1e30f;
            #pragma unroll
            for (int mt = 0; mt < 2; ++mt)
                if (mt < mts)
                    #pragma unroll
                    for (int r = 0; r < 16; ++r) {
                        float v = st[mt][r];
                        if (dtile) {
                            int kglob = kt * 64 + mt * 32 + (r & 3) + 8 * (r >> 2) + 4 * h5;
                            if (kglob > qg) v = -1e30f;
                        }
                        st[mt][r] = v;
                        pmax = fmaxf(pmax, v);
                    }
            pmax = fmaxf(pmax, __shfl_xor(pmax, 32));
            if (!__all(pmax - m_run <= 181.019336f)) {
                float mn = fmaxf(m_run, pmax);
                float al = __expf((m_run - mn) * cs);
                l_run *= al;
                #pragma unroll
                for (int r = 0; r < 16; ++r) {
                    int qloc = (r & 3) + 8 * (r >> 2) + 4 * h5;
                    float alr = __shfl(al, qloc);
                    Oa0[r] *= alr; Oa1[r] *= alr;
                }
                m_run = mn;
            }
            float ls = 0.f;
            u32 pk[2][8];
            #pragma unroll
            for (int mt = 0; mt < 2; ++mt)
                if (mt < mts)
                    #pragma unroll
                    for (int w = 0; w < 8; ++w) {
                        float p0 = __expf((st[mt][2 * w]     - m_run) * cs);
                        float p1 = __expf((st[mt][2 * w + 1] - m_run) * cs);
                        ls += p0 + p1;
                        pk[mt][w] = (u32)f2bn(p0) | ((u32)f2bn(p1) << 16);
                    }
            l_run += ls + __shfl_xor(ls, 32);
            __builtin_amdgcn_s_setprio(1);
            #pragma unroll
            for (int mt = 0; mt < 2; ++mt)
                if (mt < mts) {
                    u32 pko[8];
                    #pragma unroll
                    for (int w = 0; w < 8; ++w)
                        pko[w] = __shfl_xor(pk[mt][w], 32);
                    #pragma unroll
                    for (int kbl = 0; kbl < 2; ++kbl) {
                        int kb = mt * 2 + kbl;
                        u32x4 aw;
                        #pragma unroll
                        for (int w = 0; w < 4; ++w) {
                            int widx = 4 * kbl + 2 * h5 + (w & 1);
                            bool own = (w < 2) != (h5 == 1);
                            aw[w] = own ? pk[mt][widx] : pko[widx];
                        }
                        bf16x8 af = __builtin_bit_cast(bf16x8, aw);
                        #pragma unroll
                        for (int dt = 0; dt < 2; ++dt) {
                            int r = dt * 32 + l31;
                            int byte = (r * 128 + (kb * 16 + h5 * 8) * 2) ^ ((r & 7) << 4);
                            bf16x8 vf = *(const bf16x8*)((char*)Vc + byte);
                            if (dt == 0) Oa0 = __builtin_amdgcn_mfma_f32_32x32x16_bf16(af, vf, Oa0, 0, 0, 0);
                            else         Oa1 = __builtin_amdgcn_mfma_f32_32x32x16_bf16(af, vf, Oa1, 0, 0, 0);
                        }
                    }
                }
            __builtin_amdgcn_s_setprio(0);
        }
        if (pf) {
            u16* Kn = Ks[cur ^ 1];
            u16* Vn = Vs[cur ^ 1];
            *(bf16x8*)((char*)Kn + byteA) = kA;
            *(bf16x8*)((char*)Kn + byteB) = kB;
            *(bf16x8*)((char*)Vn + byteA) = vA;
            *(bf16x8*)((char*)Vn + byteB) = vB;
        }
        __syncthreads();
    }
    float rln = 1.f / l_run;
    u16* obase = o + (size_t)(b * Ssz) * Dsz + hh * 64;
    #pragma unroll
    for (int r = 0; r < 16; ++r) {
        int qloc = (r & 3) + 8 * (r >> 2) + 4 * h5;
        float s = __shfl(rln, qloc);
        u16* orow = obase + (size_t)(g * 32 + qloc) * Dsz + l31;
        orow[0]  = f2bn(Oa0[r] * s);
        orow[32] = f2bn(Oa1[r] * s);
    }
}

// ---------------- host ----------------
extern "C" void kernel_launch(void* const* d_in, const int* in_sizes, int n_in,
                              void* d_out, int out_size, void* d_ws, size_t ws_size,
                              hipStream_t stream) {
    (void)in_sizes; (void)n_in; (void)out_size; (void)ws_size;
    const int*   tokens = (const int*)d_in[0];
    const float* embed  = (const float*)d_in[1];
    const float* wq     = (const float*)d_in[2];
    const float* wk     = (const float*)d_in[3];
    const float* wv     = (const float*)d_in[4];
    const float* wo     = (const float*)d_in[5];
    const float* bo     = (const float*)d_in[6];
    const float* w1     = (const float*)d_in[7];
    const float* b1     = (const float*)d_in[8];
    const float* w2     = (const float*)d_in[9];
    const float* b2     = (const float*)d_in[10];
    const float* ln_g   = (const float*)d_in[11];
    const float* ln_b   = (const float*)d_in[12];
    const float* lnf_g  = (const float*)d_in[13];
    const float* lnf_b  = (const float*)d_in[14];
    const float* w_out  = (const float*)d_in[15];
    const float* b_out  = (const float*)d_in[16];
    float* out = (float*)d_out;

    char* ws = (char*)d_ws;
    size_t off = 0;
    auto alloc = [&](size_t bytes) {
        void* p = ws + off;
        off += (bytes + 255) & ~(size_t)255;
        return p;
    };
    u16*   x     = (u16*)alloc((size_t)Msz * Dsz * 2);
    u16*   h     = (u16*)alloc((size_t)Msz * Dsz * 2);
    u16*   qkv   = (u16*)alloc((size_t)Msz * 1536 * 2);
    u16*   vT    = (u16*)alloc((size_t)Bsz * Hsz * 64 * Ssz * 2);
    u16*   ob    = (u16*)alloc((size_t)Msz * Dsz * 2);
    u16*   ffh   = (u16*)alloc((size_t)Msz * FFsz * 2);
    u16*   wqkvT = (u16*)alloc((size_t)Lsz * 3 * Dsz * Dsz * 2);
    u16*   woT   = (u16*)alloc((size_t)Lsz * Dsz * Dsz * 2);
    u16*   w1T   = (u16*)alloc((size_t)Lsz * FFsz * Dsz * 2);
    u16*   w2T   = (u16*)alloc((size_t)Lsz * Dsz * FFsz * 2);
    u16*   w_outT= (u16*)alloc((size_t)VszPad * Dsz * 2);

    dim3 tb(256);
    size_t dd = (size_t)Dsz * Dsz;
    hipMemsetAsync(w_outT + (size_t)Vsz * Dsz, 0, (size_t)(VszPad - Vsz) * Dsz * 2, stream);
    tconvqkv_kernel<<<dim3(16, 16, Lsz * 3), tb, 0, stream>>>(wq, wk, wv, wqkvT);
    tconv_kernel<<<dim3(16, 16, Lsz), tb, 0, stream>>>(wo, woT, Dsz, Dsz, dd, dd);
    tconv_kernel<<<dim3(64, 16, Lsz), tb, 0, stream>>>(w1, w1T, Dsz, FFsz, (size_t)Dsz * FFsz, (size_t)FFsz * Dsz);
    tconv_kernel<<<dim3(16, 64, Lsz), tb, 0, stream>>>(w2, w2T, FFsz, Dsz, (size_t)FFsz * Dsz, (size_t)Dsz * FFsz);
    tconv_kernel<<<dim3(250, 16, 1), tb, 0, stream>>>(w_out, w_outT, Dsz, Vsz, 0, 0);

    embed_kernel<<<Msz * 256 / 256, tb, 0, stream>>>(tokens, embed, x);

    for (int l = 0; l < Lsz; ++l) {
        ln_kernel<<<Msz / 4, tb, 0, stream>>>(x, ln_g + l * Dsz, ln_b + l * Dsz, h);
        // qkv: pipelined 256x128 tile -> grid must cover N=1536 with 128-wide n-blocks: gx=12
        gemmP_kernel<false, false, false, true, false, true><<<dim3(12, Msz / 256), dim3(512), 0, stream>>>(
            h, wqkvT + (size_t)l * 3 * dd, nullptr, nullptr, qkv, vT, Msz, 1536, Dsz);
        flash5_kernel<<<dim3(512), tb, 0, stream>>>(qkv, vT, ob);
        gemm_kernel<true, true, false, false, true, false, 2, false><<<dim3(4, Msz / 64), tb, 0, stream>>>(
            ob, woT + (size_t)l * dd, bo + l * Dsz, x, nullptr, x, nullptr, Msz, Dsz, Dsz);
        ln_kernel<<<Msz / 4, tb, 0, stream>>>(x, ln_g + l * Dsz, ln_b + l * Dsz, h);
        // ffn1: pipelined 256x128, M-stripe (16 n-blocks x 128 = 2048 ✓)
        gemmP_kernel<true, true, false, true, false, false><<<dim3(16, Msz / 256), dim3(512), 0, stream>>>(
            h, w1T + (size_t)l * FFsz * Dsz, b1 + l * FFsz, nullptr, ffh, nullptr, Msz, FFsz, Dsz);
        gemm_kernel<true, true, false, false, true, false, 2, false><<<dim3(4, Msz / 64), tb, 0, stream>>>(
            ffh, w2T + (size_t)l * Dsz * FFsz, b2 + l * Dsz, x, nullptr, x, nullptr, Msz, Dsz, FFsz);
    }
    ln_kernel<<<Msz / 4, tb, 0, stream>>>(x, lnf_g, lnf_b, h);
    // logits: pipelined 256x128, XN map (64 n-blocks x 128 = 8192 ✓)
    gemmP_kernel<true, false, true, false, true, false><<<dim3(VszPad / 128, Msz / 256), dim3(512), 0, stream>>>(
        h, w_outT, b_out, out, nullptr, nullptr, Msz, Vsz, Dsz);
}

// Round 14
// 1543.608 us; speedup vs baseline: 1.0732x; 1.0732x over previous
//
#include <hip/hip_runtime.h>

#define Bsz 4
#define Ssz 2048
#define Dsz 512
#define Hsz 8
#define Lsz 6
#define Vsz 8000
#define FFsz 2048
#define Msz (Bsz*Ssz)
#define VszPad 8192

typedef unsigned short u16;
typedef unsigned int u32;
typedef __attribute__((ext_vector_type(8))) short bf16x8;
typedef __attribute__((ext_vector_type(4))) float f32x4;
typedef __attribute__((ext_vector_type(16))) float f32x16;
typedef __attribute__((ext_vector_type(4))) u32 u32x4;
typedef __attribute__((ext_vector_type(4))) u16 u16x4;

__device__ __forceinline__ u16 f2b(float f) {
    union { float f; unsigned u; } x; x.f = f;
    return (u16)((x.u + 0x7fffu + ((x.u >> 16) & 1u)) >> 16);
}
__device__ __forceinline__ float b2f(u16 v) {
    union { u32 u; float f; } x; x.u = ((u32)v) << 16; return x.f;
}

#define GLOAD_LDS16(g, l) __builtin_amdgcn_global_load_lds( \
    (const __attribute__((address_space(1))) u32*)(g), \
    (__attribute__((address_space(3))) u32*)(l), 16, 0, 0)

// ---------------- embedding + positional encoding (bf16 out) ----------------
__global__ __launch_bounds__(256) void embed_kernel(const int* __restrict__ tokens,
                                                    const float* __restrict__ embed,
                                                    u16* __restrict__ x) {
    int idx = blockIdx.x * 256 + threadIdx.x;
    int row = idx >> 8, p = idx & 255;
    int tok = tokens[row];
    int s = row & (Ssz - 1);
    float div = __expf((float)p * (-9.210340371976184f / 256.f));
    float ang = (float)s * div;
    float2 e = ((const float2*)(embed + (size_t)tok * Dsz))[p];
    u32 o = (u32)f2b(e.x + sinf(ang)) | ((u32)f2b(e.y + cosf(ang)) << 16);
    ((u32*)(x + (size_t)row * Dsz))[p] = o;
}

// ---------------- layernorm (bf16 in -> bf16 out), 1 wave per row ----------------
__global__ __launch_bounds__(256) void ln_kernel(const u16* __restrict__ x,
                                                 const float* __restrict__ g,
                                                 const float* __restrict__ bta,
                                                 u16* __restrict__ out) {
    int wave = threadIdx.x >> 6, lane = threadIdx.x & 63;
    int row = blockIdx.x * 4 + wave;
    bf16x8 a = ((const bf16x8*)(x + (size_t)row * Dsz))[lane];
    float vals[8];
    #pragma unroll
    for (int i = 0; i < 8; ++i) vals[i] = b2f((u16)a[i]);
    float s = 0.f;
    #pragma unroll
    for (int i = 0; i < 8; ++i) s += vals[i];
    #pragma unroll
    for (int o = 32; o; o >>= 1) s += __shfl_xor(s, o);
    float mean = s * (1.f / 512.f);
    float sq = 0.f;
    #pragma unroll
    for (int i = 0; i < 8; ++i) { float d = vals[i] - mean; sq += d * d; }
    #pragma unroll
    for (int o = 32; o; o >>= 1) sq += __shfl_xor(sq, o);
    float rstd = rsqrtf(sq * (1.f / 512.f) + 1e-5f);
    int base = lane * 8;
    bf16x8 rv;
    #pragma unroll
    for (int i = 0; i < 8; ++i)
        rv[i] = (short)f2b((vals[i] - mean) * rstd * g[base + i] + bta[base + i]);
    *(bf16x8*)(out + (size_t)row * Dsz + base) = rv;
}

// ---------------- tiled transpose + fp32->bf16 convert: src[R,C] -> dst[C,R] ----------------
__global__ __launch_bounds__(256) void tconv_kernel(const float* __restrict__ src,
                                                    u16* __restrict__ dst,
                                                    int R, int C,
                                                    size_t sstride, size_t dstride) {
    __shared__ float tile[32][33];
    const float* s = src + blockIdx.z * sstride;
    u16* d = dst + blockIdx.z * dstride;
    int c0 = blockIdx.x * 32, r0 = blockIdx.y * 32;
    int tx = threadIdx.x & 31, ty = threadIdx.x >> 5;
    #pragma unroll
    for (int i = 0; i < 32; i += 8)
        tile[ty + i][tx] = s[(size_t)(r0 + ty + i) * C + c0 + tx];
    __syncthreads();
    #pragma unroll
    for (int i = 0; i < 32; i += 8)
        d[(size_t)(c0 + ty + i) * R + r0 + tx] = f2b(tile[tx][ty + i]);
}

// ---------------- merged wq/wk/wv transpose (3L z-slices in one launch) ----------------
__global__ __launch_bounds__(256) void tconvqkv_kernel(const float* __restrict__ wq,
                                                       const float* __restrict__ wk,
                                                       const float* __restrict__ wv,
                                                       u16* __restrict__ dst) {
    __shared__ float tile[32][33];
    int z = blockIdx.z, which = z / Lsz, l = z % Lsz;
    const float* s = (which == 0 ? wq : which == 1 ? wk : wv) + (size_t)l * Dsz * Dsz;
    u16* d = dst + ((size_t)l * 3 + which) * Dsz * Dsz;
    int c0 = blockIdx.x * 32, r0 = blockIdx.y * 32;
    int tx = threadIdx.x & 31, ty = threadIdx.x >> 5;
    #pragma unroll
    for (int i = 0; i < 32; i += 8)
        tile[ty + i][tx] = s[(size_t)(r0 + ty + i) * Dsz + c0 + tx];
    __syncthreads();
    #pragma unroll
    for (int i = 0; i < 32; i += 8)
        d[(size_t)(c0 + ty + i) * Dsz + r0 + tx] = f2b(tile[tx][ty + i]);
}

// ---------------- bf16 MFMA GEMM (m97 structure + XCD working-set ordering + BMF tile) ----------------
// BMF=4: 128x128 tile (4 blocks/CU). BMF=2: 64x128 tile for the N=512 GEMMs.
// QKV=true: output cols >=1024 are V -> written TRANSPOSED into vT (fuses vtrans kernel).
template<bool BIAS, bool RES, bool RELU, bool OF32, bool OBF16, bool XN, int BMF, bool QKV>
__global__ __launch_bounds__(256, 4) void gemm_kernel(const u16* __restrict__ A,
                                                   const u16* __restrict__ BT,
                                                   const float* __restrict__ bias,
                                                   const u16* __restrict__ res,
                                                   float* __restrict__ outf,
                                                   u16* __restrict__ outb,
                                                   u16* __restrict__ vT,
                                                   int M, int N, int K) {
    __shared__ u16 As[BMF * 32 * 64];
    __shared__ u16 Bs[128 * 64];
    int tid = threadIdx.x;
    int wave = tid >> 6, lane = tid & 63;
    int wm = wave >> 1, wn = wave & 1;
    int gx = gridDim.x;
    int bid = blockIdx.y * gx + blockIdx.x;
    int xcd = bid & 7, j = bid >> 3;
    int mblk, nblk;
    if (XN) { mblk = j >> 3; nblk = xcd * 8 + (j & 7); }       // gx must be 64
    else    { int sm = gridDim.y >> 3; mblk = xcd * sm + j / gx; nblk = j % gx; }
    int m0 = mblk * (BMF * 32), n0 = nblk * 128;
    int lr = lane & 15, lg = lane >> 4;
    int srow = lane >> 3;
    int scol = (lane & 7) * 8;
    f32x4 acc[BMF][4] = {};
    for (int k0 = 0; k0 < K; k0 += 64) {
        #pragma unroll
        for (int i = 0; i < BMF; ++i) {
            int chunk = wave * BMF + i;
            int r = chunk * 8 + srow;
            GLOAD_LDS16(A + (size_t)(m0 + r) * K + k0 + scol, &As[chunk * 512]);
        }
        #pragma unroll
        for (int i = 0; i < 4; ++i) {
            int chunk = wave * 4 + i;
            int r = chunk * 8 + srow;
            GLOAD_LDS16(BT + (size_t)(n0 + r) * K + k0 + scol, &Bs[chunk * 512]);
        }
        __syncthreads();
        #pragma unroll
        for (int kk = 0; kk < 2; ++kk) {
            bf16x8 af[BMF], bfr[4];
            #pragma unroll
            for (int m = 0; m < BMF; ++m)
                af[m] = *(const bf16x8*)(As + (wm * (BMF * 16) + m * 16 + lr) * 64 + kk * 32 + lg * 8);
            #pragma unroll
            for (int n = 0; n < 4; ++n)
                bfr[n] = *(const bf16x8*)(Bs + (wn * 64 + n * 16 + lr) * 64 + kk * 32 + lg * 8);
            #pragma unroll
            for (int m = 0; m < BMF; ++m)
                #pragma unroll
                for (int n = 0; n < 4; ++n)
                    acc[m][n] = __builtin_amdgcn_mfma_f32_16x16x32_bf16(af[m], bfr[n], acc[m][n], 0, 0, 0);
        }
        __syncthreads();
    }
    #pragma unroll
    for (int m = 0; m < BMF; ++m) {
        int row = m0 + wm * (BMF * 16) + m * 16 + lg * 4;
        #pragma unroll
        for (int n = 0; n < 4; ++n) {
            int col = n0 + wn * 64 + n * 16 + lr;
            if (QKV && col >= 1024) {
                // V block: write transposed into vT[(b*8+hh)*64+hd][s] (4 contiguous s, 8B store)
                int hd = col - 1024;
                int hh = hd >> 6; hd &= 63;
                int b = row >> 11, s = row & 2047;
                u16x4 v4;
                #pragma unroll
                for (int j2 = 0; j2 < 4; ++j2) v4[j2] = f2b(acc[m][n][j2]);
                *(u16x4*)(vT + ((size_t)(b * 8 + hh) * 64 + hd) * Ssz + s) = v4;
            } else if (col < N) {
                float bv = BIAS ? bias[col] : 0.f;
                #pragma unroll
                for (int j2 = 0; j2 < 4; ++j2) {
                    float v = acc[m][n][j2] + bv;
                    if (RES) v += b2f(res[(size_t)(row + j2) * N + col]);
                    if (RELU) v = fmaxf(v, 0.f);
                    if (OF32) outf[(size_t)(row + j2) * N + col] = v;
                    if (OBF16) outb[(size_t)(row + j2) * N + col] = f2b(v);
                }
            }
        }
    }
}

// ---------------- flash attention v5: double-buffered K/V + async-stage, 1 barrier/tile ----------------
__global__ __launch_bounds__(256, 2) void flash5_kernel(const u16* __restrict__ qkv,
                                                        const u16* __restrict__ vT,
                                                        u16* __restrict__ o) {
    __shared__ u16 Ks[2][64 * 64];
    __shared__ u16 Vs[2][64 * 64];
    int blk = blockIdx.x;
    int bh = blk & 31;                 // bh%8 -> stable XCD affinity
    int c = 15 - (blk >> 5);           // heavy-first
    int b = bh >> 3, hh = bh & 7;
    int tid = threadIdx.x, wave = tid >> 6, lane = tid & 63;
    int l31 = lane & 31, h5 = lane >> 5;
    int g = c * 4 + wave;              // this wave's q-group
    int qg = g * 32 + l31;
    int ext = (g >> 1) + 1;            // wave's k-tile extent
    int nt = 2 * c + 2;                // block's k-tile count (max extent)
    const float cs = 0.044194173824159216f;  // 1/sqrt(512)

    bf16x8 qf[4];
    {
        const u16* qrow = qkv + (size_t)(b * Ssz + qg) * 1536 + hh * 64;
        #pragma unroll
        for (int cb = 0; cb < 4; ++cb)
            qf[cb] = *(const bf16x8*)(qrow + cb * 16 + h5 * 8);
    }
    f32x16 Oa0 = {}, Oa1 = {};
    float m_run = -1e30f, l_run = 0.f;
    int sr = tid >> 3;                 // 0..31 staging row
    int sc2 = (tid & 7) * 8;           // staging col (elements)
    const u16* kbase = qkv + (size_t)(b * Ssz) * 1536 + 512 + hh * 64;
    const u16* vbase = vT + (size_t)bh * 64 * Ssz;
    int byteA = (sr * 128 + sc2 * 2) ^ ((sr & 7) << 4);          // rows 0..31
    int byteB = ((sr + 32) * 128 + sc2 * 2) ^ ((sr & 7) << 4);   // rows 32..63

    // prologue: stage tile 0 into buf 0
    {
        bf16x8 kA = *(const bf16x8*)(kbase + (size_t)sr * 1536 + sc2);
        bf16x8 kB = *(const bf16x8*)(kbase + (size_t)(32 + sr) * 1536 + sc2);
        bf16x8 vA = *(const bf16x8*)(vbase + (size_t)sr * Ssz + sc2);
        bf16x8 vB = *(const bf16x8*)(vbase + (size_t)(32 + sr) * Ssz + sc2);
        *(bf16x8*)((char*)Ks[0] + byteA) = kA;
        *(bf16x8*)((char*)Ks[0] + byteB) = kB;
        *(bf16x8*)((char*)Vs[0] + byteA) = vA;
        *(bf16x8*)((char*)Vs[0] + byteB) = vB;
    }
    __syncthreads();

    for (int kt = 0; kt < nt; ++kt) {
        int cur = kt & 1;
        bool pf = (kt + 1 < nt);
        // ---- issue next-tile global loads EARLY (latency hides under compute) ----
        bf16x8 kA, kB, vA, vB;
        if (pf) {
            kA = *(const bf16x8*)(kbase + (size_t)((kt + 1) * 64 + sr) * 1536 + sc2);
            kB = *(const bf16x8*)(kbase + (size_t)((kt + 1) * 64 + 32 + sr) * 1536 + sc2);
            vA = *(const bf16x8*)(vbase + (size_t)sr * Ssz + (kt + 1) * 64 + sc2);
            vB = *(const bf16x8*)(vbase + (size_t)(32 + sr) * Ssz + (kt + 1) * 64 + sc2);
        }
        const u16* Kc = Ks[cur];
        const u16* Vc = Vs[cur];
        if (kt < ext) {
            bool dtile = (kt == ext - 1);
            int mts = (dtile && !(g & 1)) ? 1 : 2;   // even g: mt=1 of diag tile fully masked
            // ---- QK^T (swapped) ----
            f32x16 st[2] = {};
            __builtin_amdgcn_s_setprio(1);
            #pragma unroll
            for (int mt = 0; mt < 2; ++mt)
                if (mt < mts) {
                    int r = mt * 32 + l31;
                    #pragma unroll
                    for (int cb = 0; cb < 4; ++cb) {
                        int byte = (r * 128 + (cb * 16 + h5 * 8) * 2) ^ ((r & 7) << 4);
                        bf16x8 kf = *(const bf16x8*)((char*)Kc + byte);
                        st[mt] = __builtin_amdgcn_mfma_f32_32x32x16_bf16(kf, qf[cb], st[mt], 0, 0, 0);
                    }
                }
            __builtin_amdgcn_s_setprio(0);
            // ---- mask + row max ----
            float pmax = -1e30f;
            #pragma unroll
            for (int mt = 0; mt < 2; ++mt)
                if (mt < mts)
                    #pragma unroll
                    for (int r = 0; r < 16; ++r) {
                        float v = st[mt][r];
                        if (dtile) {
                            int kglob = kt * 64 + mt * 32 + (r & 3) + 8 * (r >> 2) + 4 * h5;
                            if (kglob > qg) v = -1e30f;
                        }
                        st[mt][r] = v;
                        pmax = fmaxf(pmax, v);
                    }
            pmax = fmaxf(pmax, __shfl_xor(pmax, 32));
            // ---- defer-max rescale (THR = 8/cs = 181 raw) ----
            if (!__all(pmax - m_run <= 181.019336f)) {
                float mn = fmaxf(m_run, pmax);
                float al = __expf((m_run - mn) * cs);
                l_run *= al;
                #pragma unroll
                for (int r = 0; r < 16; ++r) {
                    int qloc = (r & 3) + 8 * (r >> 2) + 4 * h5;
                    float alr = __shfl(al, qloc);
                    Oa0[r] *= alr; Oa1[r] *= alr;
                }
                m_run = mn;
            }
            // ---- P = exp(cs*(s-m)), row sum, pack bf16 ----
            float ls = 0.f;
            u32 pk[2][8];
            #pragma unroll
            for (int mt = 0; mt < 2; ++mt)
                if (mt < mts)
                    #pragma unroll
                    for (int w = 0; w < 8; ++w) {
                        float p0 = __expf((st[mt][2 * w]     - m_run) * cs);
                        float p1 = __expf((st[mt][2 * w + 1] - m_run) * cs);
                        ls += p0 + p1;
                        pk[mt][w] = (u32)f2b(p0) | ((u32)f2b(p1) << 16);
                    }
            l_run += ls + __shfl_xor(ls, 32);
            // ---- PV ----
            __builtin_amdgcn_s_setprio(1);
            #pragma unroll
            for (int mt = 0; mt < 2; ++mt)
                if (mt < mts) {
                    u32 pko[8];
                    #pragma unroll
                    for (int w = 0; w < 8; ++w)
                        pko[w] = __shfl_xor(pk[mt][w], 32);
                    #pragma unroll
                    for (int kbl = 0; kbl < 2; ++kbl) {
                        int kb = mt * 2 + kbl;
                        u32x4 aw;
                        #pragma unroll
                        for (int w = 0; w < 4; ++w) {
                            int widx = 4 * kbl + 2 * h5 + (w & 1);
                            bool own = (w < 2) != (h5 == 1);
                            aw[w] = own ? pk[mt][widx] : pko[widx];
                        }
                        bf16x8 af = __builtin_bit_cast(bf16x8, aw);
                        #pragma unroll
                        for (int dt = 0; dt < 2; ++dt) {
                            int r = dt * 32 + l31;
                            int byte = (r * 128 + (kb * 16 + h5 * 8) * 2) ^ ((r & 7) << 4);
                            bf16x8 vf = *(const bf16x8*)((char*)Vc + byte);
                            if (dt == 0) Oa0 = __builtin_amdgcn_mfma_f32_32x32x16_bf16(af, vf, Oa0, 0, 0, 0);
                            else         Oa1 = __builtin_amdgcn_mfma_f32_32x32x16_bf16(af, vf, Oa1, 0, 0, 0);
                        }
                    }
                }
            __builtin_amdgcn_s_setprio(0);
        }
        // ---- write next tile into the other buffer (after compute; loads have landed) ----
        if (pf) {
            u16* Kn = Ks[cur ^ 1];
            u16* Vn = Vs[cur ^ 1];
            *(bf16x8*)((char*)Kn + byteA) = kA;
            *(bf16x8*)((char*)Kn + byteB) = kB;
            *(bf16x8*)((char*)Vn + byteA) = vA;
            *(bf16x8*)((char*)Vn + byteB) = vB;
        }
        __syncthreads();   // next buf visible; cur reads done before its overwrite next iter
    }
    // ---- epilogue ----
    float rln = 1.f / l_run;
    u16* obase = o + (size_t)(b * Ssz) * Dsz + hh * 64;
    #pragma unroll
    for (int r = 0; r < 16; ++r) {
        int qloc = (r & 3) + 8 * (r >> 2) + 4 * h5;
        float s = __shfl(rln, qloc);
        u16* orow = obase + (size_t)(g * 32 + qloc) * Dsz + l31;
        orow[0]  = f2b(Oa0[r] * s);
        orow[32] = f2b(Oa1[r] * s);
    }
}

// ---------------- host ----------------
extern "C" void kernel_launch(void* const* d_in, const int* in_sizes, int n_in,
                              void* d_out, int out_size, void* d_ws, size_t ws_size,
                              hipStream_t stream) {
    (void)in_sizes; (void)n_in; (void)out_size; (void)ws_size;
    const int*   tokens = (const int*)d_in[0];
    const float* embed  = (const float*)d_in[1];
    const float* wq     = (const float*)d_in[2];
    const float* wk     = (const float*)d_in[3];
    const float* wv     = (const float*)d_in[4];
    const float* wo     = (const float*)d_in[5];
    const float* bo     = (const float*)d_in[6];
    const float* w1     = (const float*)d_in[7];
    const float* b1     = (const float*)d_in[8];
    const float* w2     = (const float*)d_in[9];
    const float* b2     = (const float*)d_in[10];
    const float* ln_g   = (const float*)d_in[11];
    const float* ln_b   = (const float*)d_in[12];
    const float* lnf_g  = (const float*)d_in[13];
    const float* lnf_b  = (const float*)d_in[14];
    const float* w_out  = (const float*)d_in[15];
    const float* b_out  = (const float*)d_in[16];
    float* out = (float*)d_out;

    char* ws = (char*)d_ws;
    size_t off = 0;
    auto alloc = [&](size_t bytes) {
        void* p = ws + off;
        off += (bytes + 255) & ~(size_t)255;
        return p;
    };
    u16*   x     = (u16*)alloc((size_t)Msz * Dsz * 2);
    u16*   h     = (u16*)alloc((size_t)Msz * Dsz * 2);
    u16*   qkv   = (u16*)alloc((size_t)Msz * 1536 * 2);
    u16*   vT    = (u16*)alloc((size_t)Bsz * Hsz * 64 * Ssz * 2);
    u16*   ob    = (u16*)alloc((size_t)Msz * Dsz * 2);
    u16*   ffh   = (u16*)alloc((size_t)Msz * FFsz * 2);
    u16*   wqkvT = (u16*)alloc((size_t)Lsz * 3 * Dsz * Dsz * 2);
    u16*   woT   = (u16*)alloc((size_t)Lsz * Dsz * Dsz * 2);
    u16*   w1T   = (u16*)alloc((size_t)Lsz * FFsz * Dsz * 2);
    u16*   w2T   = (u16*)alloc((size_t)Lsz * Dsz * FFsz * 2);
    u16*   w_outT= (u16*)alloc((size_t)VszPad * Dsz * 2);

    dim3 tb(256);
    size_t dd = (size_t)Dsz * Dsz;
    // zero the logits-weight pad rows (rows 8000..8191) so OOB-free staging
    hipMemsetAsync(w_outT + (size_t)Vsz * Dsz, 0, (size_t)(VszPad - Vsz) * Dsz * 2, stream);
    tconvqkv_kernel<<<dim3(16, 16, Lsz * 3), tb, 0, stream>>>(wq, wk, wv, wqkvT);
    tconv_kernel<<<dim3(16, 16, Lsz), tb, 0, stream>>>(wo, woT, Dsz, Dsz, dd, dd);
    tconv_kernel<<<dim3(64, 16, Lsz), tb, 0, stream>>>(w1, w1T, Dsz, FFsz, (size_t)Dsz * FFsz, (size_t)FFsz * Dsz);
    tconv_kernel<<<dim3(16, 64, Lsz), tb, 0, stream>>>(w2, w2T, FFsz, Dsz, (size_t)FFsz * Dsz, (size_t)Dsz * FFsz);
    tconv_kernel<<<dim3(250, 16, 1), tb, 0, stream>>>(w_out, w_outT, Dsz, Vsz, 0, 0);

    embed_kernel<<<Msz * 256 / 256, tb, 0, stream>>>(tokens, embed, x);

    for (int l = 0; l < Lsz; ++l) {
        ln_kernel<<<Msz / 4, tb, 0, stream>>>(x, ln_g + l * Dsz, ln_b + l * Dsz, h);
        // qkv: 128^2 tile, M-stripe map; Q/K -> qkv buffer, V -> vT transposed (fused)
        gemm_kernel<false, false, false, false, true, false, 4, true><<<dim3(12, Msz / 128), tb, 0, stream>>>(
            h, wqkvT + (size_t)l * 3 * dd, nullptr, nullptr, nullptr, qkv, vT, Msz, 1536, Dsz);
        flash5_kernel<<<dim3(512), tb, 0, stream>>>(qkv, vT, ob);
        gemm_kernel<true, true, false, false, true, false, 2, false><<<dim3(4, Msz / 64), tb, 0, stream>>>(
            ob, woT + (size_t)l * dd, bo + l * Dsz, x, nullptr, x, nullptr, Msz, Dsz, Dsz);
        ln_kernel<<<Msz / 4, tb, 0, stream>>>(x, ln_g + l * Dsz, ln_b + l * Dsz, h);
        gemm_kernel<true, false, true, false, true, false, 4, false><<<dim3(16, Msz / 128), tb, 0, stream>>>(
            h, w1T + (size_t)l * FFsz * Dsz, b1 + l * FFsz, nullptr, nullptr, ffh, nullptr, Msz, FFsz, Dsz);
        gemm_kernel<true, true, false, false, true, false, 2, false><<<dim3(4, Msz / 64), tb, 0, stream>>>(
            ffh, w2T + (size_t)l * Dsz * FFsz, b2 + l * Dsz, x, nullptr, x, nullptr, Msz, Dsz, FFsz);
    }
    ln_kernel<<<Msz / 4, tb, 0, stream>>>(x, lnf_g, lnf_b, h);
    gemm_kernel<true, false, false, true, false, true, 4, false><<<dim3(64, Msz / 128), tb, 0, stream>>>(
        h, w_outT, b_out, nullptr, out, nullptr, nullptr, Msz, Vsz, Dsz);
}

// Round 15
// 1484.060 us; speedup vs baseline: 1.1162x; 1.0401x over previous
//
#include <hip/hip_runtime.h>

#define Bsz 4
#define Ssz 2048
#define Dsz 512
#define Hsz 8
#define Lsz 6
#define Vsz 8000
#define FFsz 2048
#define Msz (Bsz*Ssz)
#define VszPad 8192

typedef unsigned short u16;
typedef unsigned int u32;
typedef __attribute__((ext_vector_type(8))) short bf16x8;
typedef __attribute__((ext_vector_type(4))) float f32x4;
typedef __attribute__((ext_vector_type(16))) float f32x16;
typedef __attribute__((ext_vector_type(4))) u32 u32x4;
typedef __attribute__((ext_vector_type(4))) u16 u16x4;

__device__ __forceinline__ u16 f2b(float f) {
    union { float f; unsigned u; } x; x.f = f;
    return (u16)((x.u + 0x7fffu + ((x.u >> 16) & 1u)) >> 16);
}
__device__ __forceinline__ float b2f(u16 v) {
    union { u32 u; float f; } x; x.u = ((u32)v) << 16; return x.f;
}

#define GLOAD_LDS16(g, l) __builtin_amdgcn_global_load_lds( \
    (const __attribute__((address_space(1))) u32*)(g), \
    (__attribute__((address_space(3))) u32*)(l), 16, 0, 0)

// ---------------- embedding + positional encoding (bf16 out) ----------------
__global__ __launch_bounds__(256) void embed_kernel(const int* __restrict__ tokens,
                                                    const float* __restrict__ embed,
                                                    u16* __restrict__ x) {
    int idx = blockIdx.x * 256 + threadIdx.x;
    int row = idx >> 8, p = idx & 255;
    int tok = tokens[row];
    int s = row & (Ssz - 1);
    float div = __expf((float)p * (-9.210340371976184f / 256.f));
    float ang = (float)s * div;
    float2 e = ((const float2*)(embed + (size_t)tok * Dsz))[p];
    u32 o = (u32)f2b(e.x + sinf(ang)) | ((u32)f2b(e.y + cosf(ang)) << 16);
    ((u32*)(x + (size_t)row * Dsz))[p] = o;
}

// ---------------- layernorm (bf16 in -> bf16 out), 1 wave per row ----------------
__global__ __launch_bounds__(256) void ln_kernel(const u16* __restrict__ x,
                                                 const float* __restrict__ g,
                                                 const float* __restrict__ bta,
                                                 u16* __restrict__ out) {
    int wave = threadIdx.x >> 6, lane = threadIdx.x & 63;
    int row = blockIdx.x * 4 + wave;
    bf16x8 a = ((const bf16x8*)(x + (size_t)row * Dsz))[lane];
    float vals[8];
    #pragma unroll
    for (int i = 0; i < 8; ++i) vals[i] = b2f((u16)a[i]);
    float s = 0.f;
    #pragma unroll
    for (int i = 0; i < 8; ++i) s += vals[i];
    #pragma unroll
    for (int o = 32; o; o >>= 1) s += __shfl_xor(s, o);
    float mean = s * (1.f / 512.f);
    float sq = 0.f;
    #pragma unroll
    for (int i = 0; i < 8; ++i) { float d = vals[i] - mean; sq += d * d; }
    #pragma unroll
    for (int o = 32; o; o >>= 1) sq += __shfl_xor(sq, o);
    float rstd = rsqrtf(sq * (1.f / 512.f) + 1e-5f);
    int base = lane * 8;
    bf16x8 rv;
    #pragma unroll
    for (int i = 0; i < 8; ++i)
        rv[i] = (short)f2b((vals[i] - mean) * rstd * g[base + i] + bta[base + i]);
    *(bf16x8*)(out + (size_t)row * Dsz + base) = rv;
}

// ---------------- tiled transpose + fp32->bf16 convert: src[R,C] -> dst[C,R] ----------------
__global__ __launch_bounds__(256) void tconv_kernel(const float* __restrict__ src,
                                                    u16* __restrict__ dst,
                                                    int R, int C,
                                                    size_t sstride, size_t dstride) {
    __shared__ float tile[32][33];
    const float* s = src + blockIdx.z * sstride;
    u16* d = dst + blockIdx.z * dstride;
    int c0 = blockIdx.x * 32, r0 = blockIdx.y * 32;
    int tx = threadIdx.x & 31, ty = threadIdx.x >> 5;
    #pragma unroll
    for (int i = 0; i < 32; i += 8)
        tile[ty + i][tx] = s[(size_t)(r0 + ty + i) * C + c0 + tx];
    __syncthreads();
    #pragma unroll
    for (int i = 0; i < 32; i += 8)
        d[(size_t)(c0 + ty + i) * R + r0 + tx] = f2b(tile[tx][ty + i]);
}

// ---------------- merged wq/wk/wv transpose (3L z-slices in one launch) ----------------
__global__ __launch_bounds__(256) void tconvqkv_kernel(const float* __restrict__ wq,
                                                       const float* __restrict__ wk,
                                                       const float* __restrict__ wv,
                                                       u16* __restrict__ dst) {
    __shared__ float tile[32][33];
    int z = blockIdx.z, which = z / Lsz, l = z % Lsz;
    const float* s = (which == 0 ? wq : which == 1 ? wk : wv) + (size_t)l * Dsz * Dsz;
    u16* d = dst + ((size_t)l * 3 + which) * Dsz * Dsz;
    int c0 = blockIdx.x * 32, r0 = blockIdx.y * 32;
    int tx = threadIdx.x & 31, ty = threadIdx.x >> 5;
    #pragma unroll
    for (int i = 0; i < 32; i += 8)
        tile[ty + i][tx] = s[(size_t)(r0 + ty + i) * Dsz + c0 + tx];
    __syncthreads();
    #pragma unroll
    for (int i = 0; i < 32; i += 8)
        d[(size_t)(c0 + ty + i) * Dsz + r0 + tx] = f2b(tile[tx][ty + i]);
}

// ---------------- bf16 MFMA GEMM (m97 structure + XCD working-set ordering + BMF tile) ----------------
// BMF=4: 128x128 tile (4 blocks/CU). BMF=2: 64x128 tile for the N=512 GEMMs.
// QKV=true: output cols >=1024 are V -> written TRANSPOSED into vT (fuses vtrans kernel).
template<bool BIAS, bool RES, bool RELU, bool OF32, bool OBF16, bool XN, int BMF, bool QKV>
__global__ __launch_bounds__(256, 4) void gemm_kernel(const u16* __restrict__ A,
                                                   const u16* __restrict__ BT,
                                                   const float* __restrict__ bias,
                                                   const u16* __restrict__ res,
                                                   float* __restrict__ outf,
                                                   u16* __restrict__ outb,
                                                   u16* __restrict__ vT,
                                                   int M, int N, int K) {
    __shared__ u16 As[BMF * 32 * 64];
    __shared__ u16 Bs[128 * 64];
    int tid = threadIdx.x;
    int wave = tid >> 6, lane = tid & 63;
    int wm = wave >> 1, wn = wave & 1;
    int gx = gridDim.x;
    int bid = blockIdx.y * gx + blockIdx.x;
    int xcd = bid & 7, j = bid >> 3;
    int mblk, nblk;
    if (XN) { mblk = j >> 3; nblk = xcd * 8 + (j & 7); }       // gx must be 64
    else    { int sm = gridDim.y >> 3; mblk = xcd * sm + j / gx; nblk = j % gx; }
    int m0 = mblk * (BMF * 32), n0 = nblk * 128;
    int lr = lane & 15, lg = lane >> 4;
    int srow = lane >> 3;
    int scol = (lane & 7) * 8;
    f32x4 acc[BMF][4] = {};
    for (int k0 = 0; k0 < K; k0 += 64) {
        #pragma unroll
        for (int i = 0; i < BMF; ++i) {
            int chunk = wave * BMF + i;
            int r = chunk * 8 + srow;
            GLOAD_LDS16(A + (size_t)(m0 + r) * K + k0 + scol, &As[chunk * 512]);
        }
        #pragma unroll
        for (int i = 0; i < 4; ++i) {
            int chunk = wave * 4 + i;
            int r = chunk * 8 + srow;
            GLOAD_LDS16(BT + (size_t)(n0 + r) * K + k0 + scol, &Bs[chunk * 512]);
        }
        __syncthreads();
        #pragma unroll
        for (int kk = 0; kk < 2; ++kk) {
            bf16x8 af[BMF], bfr[4];
            #pragma unroll
            for (int m = 0; m < BMF; ++m)
                af[m] = *(const bf16x8*)(As + (wm * (BMF * 16) + m * 16 + lr) * 64 + kk * 32 + lg * 8);
            #pragma unroll
            for (int n = 0; n < 4; ++n)
                bfr[n] = *(const bf16x8*)(Bs + (wn * 64 + n * 16 + lr) * 64 + kk * 32 + lg * 8);
            #pragma unroll
            for (int m = 0; m < BMF; ++m)
                #pragma unroll
                for (int n = 0; n < 4; ++n)
                    acc[m][n] = __builtin_amdgcn_mfma_f32_16x16x32_bf16(af[m], bfr[n], acc[m][n], 0, 0, 0);
        }
        __syncthreads();
    }
    #pragma unroll
    for (int m = 0; m < BMF; ++m) {
        int row = m0 + wm * (BMF * 16) + m * 16 + lg * 4;
        #pragma unroll
        for (int n = 0; n < 4; ++n) {
            int col = n0 + wn * 64 + n * 16 + lr;
            if (QKV && col >= 1024) {
                // V block: write transposed into vT[(b*8+hh)*64+hd][s] (4 contiguous s, 8B store)
                int hd = col - 1024;
                int hh = hd >> 6; hd &= 63;
                int b = row >> 11, s = row & 2047;
                u16x4 v4;
                #pragma unroll
                for (int j2 = 0; j2 < 4; ++j2) v4[j2] = f2b(acc[m][n][j2]);
                *(u16x4*)(vT + ((size_t)(b * 8 + hh) * 64 + hd) * Ssz + s) = v4;
            } else if (col < N) {
                float bv = BIAS ? bias[col] : 0.f;
                #pragma unroll
                for (int j2 = 0; j2 < 4; ++j2) {
                    float v = acc[m][n][j2] + bv;
                    if (RES) v += b2f(res[(size_t)(row + j2) * N + col]);
                    if (RELU) v = fmaxf(v, 0.f);
                    if (OF32) outf[(size_t)(row + j2) * N + col] = v;
                    if (OBF16) outb[(size_t)(row + j2) * N + col] = f2b(v);
                }
            }
        }
    }
}

// ---------------- flash attention v6: CU-balanced chunk pairing + exp2-folded softmax ----------------
// All 512 blocks are co-resident (2/CU): round-robin placement puts blocks (i, i+256) on CU i.
// Mapping idx<8 -> c=15-idx (heavy), idx>=8 -> c=idx-8 (light) makes every CU's pair sum to
// exactly 34 k-tile rounds (was 48-4g, 71% util). exp(cs*(s-m)) computed as exp2(s*k2 - m*k2).
__global__ __launch_bounds__(256, 2) void flash6_kernel(const u16* __restrict__ qkv,
                                                        const u16* __restrict__ vT,
                                                        u16* __restrict__ o) {
    __shared__ u16 Ks[2][64 * 64];
    __shared__ u16 Vs[2][64 * 64];
    int blk = blockIdx.x;
    int bh = blk & 31;                 // bh%8 -> stable XCD affinity
    int idx = blk >> 5;                // 0..15
    int c = (idx < 8) ? (15 - idx) : (idx - 8);   // slot-complement pairing: work/CU = 34 rounds
    int b = bh >> 3, hh = bh & 7;
    int tid = threadIdx.x, wave = tid >> 6, lane = tid & 63;
    int l31 = lane & 31, h5 = lane >> 5;
    int g = c * 4 + wave;              // this wave's q-group
    int qg = g * 32 + l31;
    int ext = (g >> 1) + 1;            // wave's k-tile extent
    int nt = 2 * c + 2;                // block's k-tile count (max extent)
    const float k2 = 0.06375871867f;   // (1/sqrt(512)) * log2(e)

    bf16x8 qf[4];
    {
        const u16* qrow = qkv + (size_t)(b * Ssz + qg) * 1536 + hh * 64;
        #pragma unroll
        for (int cb = 0; cb < 4; ++cb)
            qf[cb] = *(const bf16x8*)(qrow + cb * 16 + h5 * 8);
    }
    f32x16 Oa0 = {}, Oa1 = {};
    float m_run = -1e30f, l_run = 0.f;
    int sr = tid >> 3;                 // 0..31 staging row
    int sc2 = (tid & 7) * 8;           // staging col (elements)
    const u16* kbase = qkv + (size_t)(b * Ssz) * 1536 + 512 + hh * 64;
    const u16* vbase = vT + (size_t)bh * 64 * Ssz;
    int byteA = (sr * 128 + sc2 * 2) ^ ((sr & 7) << 4);          // rows 0..31
    int byteB = ((sr + 32) * 128 + sc2 * 2) ^ ((sr & 7) << 4);   // rows 32..63

    // prologue: stage tile 0 into buf 0
    {
        bf16x8 kA = *(const bf16x8*)(kbase + (size_t)sr * 1536 + sc2);
        bf16x8 kB = *(const bf16x8*)(kbase + (size_t)(32 + sr) * 1536 + sc2);
        bf16x8 vA = *(const bf16x8*)(vbase + (size_t)sr * Ssz + sc2);
        bf16x8 vB = *(const bf16x8*)(vbase + (size_t)(32 + sr) * Ssz + sc2);
        *(bf16x8*)((char*)Ks[0] + byteA) = kA;
        *(bf16x8*)((char*)Ks[0] + byteB) = kB;
        *(bf16x8*)((char*)Vs[0] + byteA) = vA;
        *(bf16x8*)((char*)Vs[0] + byteB) = vB;
    }
    __syncthreads();

    for (int kt = 0; kt < nt; ++kt) {
        int cur = kt & 1;
        bool pf = (kt + 1 < nt);
        // ---- issue next-tile global loads EARLY (latency hides under compute) ----
        bf16x8 kA, kB, vA, vB;
        if (pf) {
            kA = *(const bf16x8*)(kbase + (size_t)((kt + 1) * 64 + sr) * 1536 + sc2);
            kB = *(const bf16x8*)(kbase + (size_t)((kt + 1) * 64 + 32 + sr) * 1536 + sc2);
            vA = *(const bf16x8*)(vbase + (size_t)sr * Ssz + (kt + 1) * 64 + sc2);
            vB = *(const bf16x8*)(vbase + (size_t)(32 + sr) * Ssz + (kt + 1) * 64 + sc2);
        }
        const u16* Kc = Ks[cur];
        const u16* Vc = Vs[cur];
        if (kt < ext) {
            bool dtile = (kt == ext - 1);
            int mts = (dtile && !(g & 1)) ? 1 : 2;   // even g: mt=1 of diag tile fully masked
            // ---- QK^T (swapped) ----
            f32x16 st[2] = {};
            __builtin_amdgcn_s_setprio(1);
            #pragma unroll
            for (int mt = 0; mt < 2; ++mt)
                if (mt < mts) {
                    int r = mt * 32 + l31;
                    #pragma unroll
                    for (int cb = 0; cb < 4; ++cb) {
                        int byte = (r * 128 + (cb * 16 + h5 * 8) * 2) ^ ((r & 7) << 4);
                        bf16x8 kf = *(const bf16x8*)((char*)Kc + byte);
                        st[mt] = __builtin_amdgcn_mfma_f32_32x32x16_bf16(kf, qf[cb], st[mt], 0, 0, 0);
                    }
                }
            __builtin_amdgcn_s_setprio(0);
            // ---- mask + row max (raw units) ----
            float pmax = -1e30f;
            #pragma unroll
            for (int mt = 0; mt < 2; ++mt)
                if (mt < mts)
                    #pragma unroll
                    for (int r = 0; r < 16; ++r) {
                        float v = st[mt][r];
                        if (dtile) {
                            int kglob = kt * 64 + mt * 32 + (r & 3) + 8 * (r >> 2) + 4 * h5;
                            if (kglob > qg) v = -1e30f;
                        }
                        st[mt][r] = v;
                        pmax = fmaxf(pmax, v);
                    }
            pmax = fmaxf(pmax, __shfl_xor(pmax, 32));
            // ---- defer-max rescale (THR = 8/cs = 181 raw) ----
            if (!__all(pmax - m_run <= 181.019336f)) {
                float mn = fmaxf(m_run, pmax);
                float al = exp2f((m_run - mn) * k2);
                l_run *= al;
                #pragma unroll
                for (int r = 0; r < 16; ++r) {
                    int qloc = (r & 3) + 8 * (r >> 2) + 4 * h5;
                    float alr = __shfl(al, qloc);
                    Oa0[r] *= alr; Oa1[r] *= alr;
                }
                m_run = mn;
            }
            // ---- P = exp2(s*k2 - m*k2): one FMA + one exp per element ----
            float mk = m_run * k2;
            float ls = 0.f;
            u32 pk[2][8];
            #pragma unroll
            for (int mt = 0; mt < 2; ++mt)
                if (mt < mts)
                    #pragma unroll
                    for (int w = 0; w < 8; ++w) {
                        float p0 = exp2f(fmaf(st[mt][2 * w],     k2, -mk));
                        float p1 = exp2f(fmaf(st[mt][2 * w + 1], k2, -mk));
                        ls += p0 + p1;
                        pk[mt][w] = (u32)f2b(p0) | ((u32)f2b(p1) << 16);
                    }
            l_run += ls + __shfl_xor(ls, 32);
            // ---- PV ----
            __builtin_amdgcn_s_setprio(1);
            #pragma unroll
            for (int mt = 0; mt < 2; ++mt)
                if (mt < mts) {
                    u32 pko[8];
                    #pragma unroll
                    for (int w = 0; w < 8; ++w)
                        pko[w] = __shfl_xor(pk[mt][w], 32);
                    #pragma unroll
                    for (int kbl = 0; kbl < 2; ++kbl) {
                        int kb = mt * 2 + kbl;
                        u32x4 aw;
                        #pragma unroll
                        for (int w = 0; w < 4; ++w) {
                            int widx = 4 * kbl + 2 * h5 + (w & 1);
                            bool own = (w < 2) != (h5 == 1);
                            aw[w] = own ? pk[mt][widx] : pko[widx];
                        }
                        bf16x8 af = __builtin_bit_cast(bf16x8, aw);
                        #pragma unroll
                        for (int dt = 0; dt < 2; ++dt) {
                            int r = dt * 32 + l31;
                            int byte = (r * 128 + (kb * 16 + h5 * 8) * 2) ^ ((r & 7) << 4);
                            bf16x8 vf = *(const bf16x8*)((char*)Vc + byte);
                            if (dt == 0) Oa0 = __builtin_amdgcn_mfma_f32_32x32x16_bf16(af, vf, Oa0, 0, 0, 0);
                            else         Oa1 = __builtin_amdgcn_mfma_f32_32x32x16_bf16(af, vf, Oa1, 0, 0, 0);
                        }
                    }
                }
            __builtin_amdgcn_s_setprio(0);
        }
        // ---- write next tile into the other buffer (after compute; loads have landed) ----
        if (pf) {
            u16* Kn = Ks[cur ^ 1];
            u16* Vn = Vs[cur ^ 1];
            *(bf16x8*)((char*)Kn + byteA) = kA;
            *(bf16x8*)((char*)Kn + byteB) = kB;
            *(bf16x8*)((char*)Vn + byteA) = vA;
            *(bf16x8*)((char*)Vn + byteB) = vB;
        }
        __syncthreads();   // next buf visible; cur reads done before its overwrite next iter
    }
    // ---- epilogue ----
    float rln = 1.f / l_run;
    u16* obase = o + (size_t)(b * Ssz) * Dsz + hh * 64;
    #pragma unroll
    for (int r = 0; r < 16; ++r) {
        int qloc = (r & 3) + 8 * (r >> 2) + 4 * h5;
        float s = __shfl(rln, qloc);
        u16* orow = obase + (size_t)(g * 32 + qloc) * Dsz + l31;
        orow[0]  = f2b(Oa0[r] * s);
        orow[32] = f2b(Oa1[r] * s);
    }
}

// ---------------- host ----------------
extern "C" void kernel_launch(void* const* d_in, const int* in_sizes, int n_in,
                              void* d_out, int out_size, void* d_ws, size_t ws_size,
                              hipStream_t stream) {
    (void)in_sizes; (void)n_in; (void)out_size; (void)ws_size;
    const int*   tokens = (const int*)d_in[0];
    const float* embed  = (const float*)d_in[1];
    const float* wq     = (const float*)d_in[2];
    const float* wk     = (const float*)d_in[3];
    const float* wv     = (const float*)d_in[4];
    const float* wo     = (const float*)d_in[5];
    const float* bo     = (const float*)d_in[6];
    const float* w1     = (const float*)d_in[7];
    const float* b1     = (const float*)d_in[8];
    const float* w2     = (const float*)d_in[9];
    const float* b2     = (const float*)d_in[10];
    const float* ln_g   = (const float*)d_in[11];
    const float* ln_b   = (const float*)d_in[12];
    const float* lnf_g  = (const float*)d_in[13];
    const float* lnf_b  = (const float*)d_in[14];
    const float* w_out  = (const float*)d_in[15];
    const float* b_out  = (const float*)d_in[16];
    float* out = (float*)d_out;

    char* ws = (char*)d_ws;
    size_t off = 0;
    auto alloc = [&](size_t bytes) {
        void* p = ws + off;
        off += (bytes + 255) & ~(size_t)255;
        return p;
    };
    u16*   x     = (u16*)alloc((size_t)Msz * Dsz * 2);
    u16*   h     = (u16*)alloc((size_t)Msz * Dsz * 2);
    u16*   qkv   = (u16*)alloc((size_t)Msz * 1536 * 2);
    u16*   vT    = (u16*)alloc((size_t)Bsz * Hsz * 64 * Ssz * 2);
    u16*   ob    = (u16*)alloc((size_t)Msz * Dsz * 2);
    u16*   ffh   = (u16*)alloc((size_t)Msz * FFsz * 2);
    u16*   wqkvT = (u16*)alloc((size_t)Lsz * 3 * Dsz * Dsz * 2);
    u16*   woT   = (u16*)alloc((size_t)Lsz * Dsz * Dsz * 2);
    u16*   w1T   = (u16*)alloc((size_t)Lsz * FFsz * Dsz * 2);
    u16*   w2T   = (u16*)alloc((size_t)Lsz * Dsz * FFsz * 2);
    u16*   w_outT= (u16*)alloc((size_t)VszPad * Dsz * 2);

    dim3 tb(256);
    size_t dd = (size_t)Dsz * Dsz;
    // zero the logits-weight pad rows (rows 8000..8191) so OOB-free staging
    hipMemsetAsync(w_outT + (size_t)Vsz * Dsz, 0, (size_t)(VszPad - Vsz) * Dsz * 2, stream);
    tconvqkv_kernel<<<dim3(16, 16, Lsz * 3), tb, 0, stream>>>(wq, wk, wv, wqkvT);
    tconv_kernel<<<dim3(16, 16, Lsz), tb, 0, stream>>>(wo, woT, Dsz, Dsz, dd, dd);
    tconv_kernel<<<dim3(64, 16, Lsz), tb, 0, stream>>>(w1, w1T, Dsz, FFsz, (size_t)Dsz * FFsz, (size_t)FFsz * Dsz);
    tconv_kernel<<<dim3(16, 64, Lsz), tb, 0, stream>>>(w2, w2T, FFsz, Dsz, (size_t)FFsz * Dsz, (size_t)Dsz * FFsz);
    tconv_kernel<<<dim3(250, 16, 1), tb, 0, stream>>>(w_out, w_outT, Dsz, Vsz, 0, 0);

    embed_kernel<<<Msz * 256 / 256, tb, 0, stream>>>(tokens, embed, x);

    for (int l = 0; l < Lsz; ++l) {
        ln_kernel<<<Msz / 4, tb, 0, stream>>>(x, ln_g + l * Dsz, ln_b + l * Dsz, h);
        // qkv: 128^2 tile, M-stripe map; Q/K -> qkv buffer, V -> vT transposed (fused)
        gemm_kernel<false, false, false, false, true, false, 4, true><<<dim3(12, Msz / 128), tb, 0, stream>>>(
            h, wqkvT + (size_t)l * 3 * dd, nullptr, nullptr, nullptr, qkv, vT, Msz, 1536, Dsz);
        flash6_kernel<<<dim3(512), tb, 0, stream>>>(qkv, vT, ob);
        gemm_kernel<true, true, false, false, true, false, 2, false><<<dim3(4, Msz / 64), tb, 0, stream>>>(
            ob, woT + (size_t)l * dd, bo + l * Dsz, x, nullptr, x, nullptr, Msz, Dsz, Dsz);
        ln_kernel<<<Msz / 4, tb, 0, stream>>>(x, ln_g + l * Dsz, ln_b + l * Dsz, h);
        gemm_kernel<true, false, true, false, true, false, 4, false><<<dim3(16, Msz / 128), tb, 0, stream>>>(
            h, w1T + (size_t)l * FFsz * Dsz, b1 + l * FFsz, nullptr, nullptr, ffh, nullptr, Msz, FFsz, Dsz);
        gemm_kernel<true, true, false, false, true, false, 2, false><<<dim3(4, Msz / 64), tb, 0, stream>>>(
            ffh, w2T + (size_t)l * Dsz * FFsz, b2 + l * Dsz, x, nullptr, x, nullptr, Msz, Dsz, FFsz);
    }
    ln_kernel<<<Msz / 4, tb, 0, stream>>>(x, lnf_g, lnf_b, h);
    gemm_kernel<true, false, false, true, false, true, 4, false><<<dim3(64, Msz / 128), tb, 0, stream>>>(
        h, w_outT, b_out, nullptr, out, nullptr, nullptr, Msz, Vsz, Dsz);
}

// Round 16
// 1482.860 us; speedup vs baseline: 1.1171x; 1.0008x over previous
//
#include <hip/hip_runtime.h>

#define Bsz 4
#define Ssz 2048
#define Dsz 512
#define Hsz 8
#define Lsz 6
#define Vsz 8000
#define FFsz 2048
#define Msz (Bsz*Ssz)
#define VszPad 8192

typedef unsigned short u16;
typedef unsigned int u32;
typedef __attribute__((ext_vector_type(8))) short bf16x8;
typedef __attribute__((ext_vector_type(4))) float f32x4;
typedef __attribute__((ext_vector_type(16))) float f32x16;
typedef __attribute__((ext_vector_type(4))) u32 u32x4;
typedef __attribute__((ext_vector_type(4))) u16 u16x4;

__device__ __forceinline__ u16 f2b(float f) {
    union { float f; unsigned u; } x; x.f = f;
    return (u16)((x.u + 0x7fffu + ((x.u >> 16) & 1u)) >> 16);
}
__device__ __forceinline__ float b2f(u16 v) {
    union { u32 u; float f; } x; x.u = ((u32)v) << 16; return x.f;
}

#define GLOAD_LDS16(g, l) __builtin_amdgcn_global_load_lds( \
    (const __attribute__((address_space(1))) u32*)(g), \
    (__attribute__((address_space(3))) u32*)(l), 16, 0, 0)

// ---------------- embedding + positional encoding (bf16 out) ----------------
__global__ __launch_bounds__(256) void embed_kernel(const int* __restrict__ tokens,
                                                    const float* __restrict__ embed,
                                                    u16* __restrict__ x) {
    int idx = blockIdx.x * 256 + threadIdx.x;
    int row = idx >> 8, p = idx & 255;
    int tok = tokens[row];
    int s = row & (Ssz - 1);
    float div = __expf((float)p * (-9.210340371976184f / 256.f));
    float ang = (float)s * div;
    float2 e = ((const float2*)(embed + (size_t)tok * Dsz))[p];
    u32 o = (u32)f2b(e.x + sinf(ang)) | ((u32)f2b(e.y + cosf(ang)) << 16);
    ((u32*)(x + (size_t)row * Dsz))[p] = o;
}

// ---------------- layernorm (bf16 in -> bf16 out), 1 wave per row ----------------
__global__ __launch_bounds__(256) void ln_kernel(const u16* __restrict__ x,
                                                 const float* __restrict__ g,
                                                 const float* __restrict__ bta,
                                                 u16* __restrict__ out) {
    int wave = threadIdx.x >> 6, lane = threadIdx.x & 63;
    int row = blockIdx.x * 4 + wave;
    bf16x8 a = ((const bf16x8*)(x + (size_t)row * Dsz))[lane];
    float vals[8];
    #pragma unroll
    for (int i = 0; i < 8; ++i) vals[i] = b2f((u16)a[i]);
    float s = 0.f;
    #pragma unroll
    for (int i = 0; i < 8; ++i) s += vals[i];
    #pragma unroll
    for (int o = 32; o; o >>= 1) s += __shfl_xor(s, o);
    float mean = s * (1.f / 512.f);
    float sq = 0.f;
    #pragma unroll
    for (int i = 0; i < 8; ++i) { float d = vals[i] - mean; sq += d * d; }
    #pragma unroll
    for (int o = 32; o; o >>= 1) sq += __shfl_xor(sq, o);
    float rstd = rsqrtf(sq * (1.f / 512.f) + 1e-5f);
    int base = lane * 8;
    bf16x8 rv;
    #pragma unroll
    for (int i = 0; i < 8; ++i)
        rv[i] = (short)f2b((vals[i] - mean) * rstd * g[base + i] + bta[base + i]);
    *(bf16x8*)(out + (size_t)row * Dsz + base) = rv;
}

// ---------------- tiled transpose + fp32->bf16 convert: src[R,C] -> dst[C,R] ----------------
__global__ __launch_bounds__(256) void tconv_kernel(const float* __restrict__ src,
                                                    u16* __restrict__ dst,
                                                    int R, int C,
                                                    size_t sstride, size_t dstride) {
    __shared__ float tile[32][33];
    const float* s = src + blockIdx.z * sstride;
    u16* d = dst + blockIdx.z * dstride;
    int c0 = blockIdx.x * 32, r0 = blockIdx.y * 32;
    int tx = threadIdx.x & 31, ty = threadIdx.x >> 5;
    #pragma unroll
    for (int i = 0; i < 32; i += 8)
        tile[ty + i][tx] = s[(size_t)(r0 + ty + i) * C + c0 + tx];
    __syncthreads();
    #pragma unroll
    for (int i = 0; i < 32; i += 8)
        d[(size_t)(c0 + ty + i) * R + r0 + tx] = f2b(tile[tx][ty + i]);
}

// ---------------- merged wq/wk/wv/wo transpose (4L z-slices in one launch) ----------------
__global__ __launch_bounds__(256) void tconvw4_kernel(const float* __restrict__ wq,
                                                      const float* __restrict__ wk,
                                                      const float* __restrict__ wv,
                                                      const float* __restrict__ wo,
                                                      u16* __restrict__ qkvT,
                                                      u16* __restrict__ woT) {
    __shared__ float tile[32][33];
    int z = blockIdx.z, which = z / Lsz, l = z % Lsz;
    const float* s = (which == 0 ? wq : which == 1 ? wk : which == 2 ? wv : wo)
                     + (size_t)l * Dsz * Dsz;
    u16* d = (which < 3) ? (qkvT + ((size_t)l * 3 + which) * Dsz * Dsz)
                         : (woT + (size_t)l * Dsz * Dsz);
    int c0 = blockIdx.x * 32, r0 = blockIdx.y * 32;
    int tx = threadIdx.x & 31, ty = threadIdx.x >> 5;
    #pragma unroll
    for (int i = 0; i < 32; i += 8)
        tile[ty + i][tx] = s[(size_t)(r0 + ty + i) * Dsz + c0 + tx];
    __syncthreads();
    #pragma unroll
    for (int i = 0; i < 32; i += 8)
        d[(size_t)(c0 + ty + i) * Dsz + r0 + tx] = f2b(tile[tx][ty + i]);
}

// ---------------- bf16 MFMA GEMM (m97 structure + XCD working-set ordering + BMF tile) ----------------
template<bool BIAS, bool RES, bool RELU, bool OF32, bool OBF16, bool XN, int BMF, bool QKV>
__global__ __launch_bounds__(256, 4) void gemm_kernel(const u16* __restrict__ A,
                                                   const u16* __restrict__ BT,
                                                   const float* __restrict__ bias,
                                                   const u16* __restrict__ res,
                                                   float* __restrict__ outf,
                                                   u16* __restrict__ outb,
                                                   u16* __restrict__ vT,
                                                   int M, int N, int K) {
    __shared__ u16 As[BMF * 32 * 64];
    __shared__ u16 Bs[128 * 64];
    int tid = threadIdx.x;
    int wave = tid >> 6, lane = tid & 63;
    int wm = wave >> 1, wn = wave & 1;
    int gx = gridDim.x;
    int bid = blockIdx.y * gx + blockIdx.x;
    int xcd = bid & 7, j = bid >> 3;
    int mblk, nblk;
    if (XN) { mblk = j >> 3; nblk = xcd * 8 + (j & 7); }       // gx must be 64
    else    { int sm = gridDim.y >> 3; mblk = xcd * sm + j / gx; nblk = j % gx; }
    int m0 = mblk * (BMF * 32), n0 = nblk * 128;
    int lr = lane & 15, lg = lane >> 4;
    int srow = lane >> 3;
    int scol = (lane & 7) * 8;
    f32x4 acc[BMF][4] = {};
    for (int k0 = 0; k0 < K; k0 += 64) {
        #pragma unroll
        for (int i = 0; i < BMF; ++i) {
            int chunk = wave * BMF + i;
            int r = chunk * 8 + srow;
            GLOAD_LDS16(A + (size_t)(m0 + r) * K + k0 + scol, &As[chunk * 512]);
        }
        #pragma unroll
        for (int i = 0; i < 4; ++i) {
            int chunk = wave * 4 + i;
            int r = chunk * 8 + srow;
            GLOAD_LDS16(BT + (size_t)(n0 + r) * K + k0 + scol, &Bs[chunk * 512]);
        }
        __syncthreads();
        #pragma unroll
        for (int kk = 0; kk < 2; ++kk) {
            bf16x8 af[BMF], bfr[4];
            #pragma unroll
            for (int m = 0; m < BMF; ++m)
                af[m] = *(const bf16x8*)(As + (wm * (BMF * 16) + m * 16 + lr) * 64 + kk * 32 + lg * 8);
            #pragma unroll
            for (int n = 0; n < 4; ++n)
                bfr[n] = *(const bf16x8*)(Bs + (wn * 64 + n * 16 + lr) * 64 + kk * 32 + lg * 8);
            #pragma unroll
            for (int m = 0; m < BMF; ++m)
                #pragma unroll
                for (int n = 0; n < 4; ++n)
                    acc[m][n] = __builtin_amdgcn_mfma_f32_16x16x32_bf16(af[m], bfr[n], acc[m][n], 0, 0, 0);
        }
        __syncthreads();
    }
    #pragma unroll
    for (int m = 0; m < BMF; ++m) {
        int row = m0 + wm * (BMF * 16) + m * 16 + lg * 4;
        #pragma unroll
        for (int n = 0; n < 4; ++n) {
            int col = n0 + wn * 64 + n * 16 + lr;
            if (QKV && col >= 1024) {
                int hd = col - 1024;
                int hh = hd >> 6; hd &= 63;
                int b = row >> 11, s = row & 2047;
                u16x4 v4;
                #pragma unroll
                for (int j2 = 0; j2 < 4; ++j2) v4[j2] = f2b(acc[m][n][j2]);
                *(u16x4*)(vT + ((size_t)(b * 8 + hh) * 64 + hd) * Ssz + s) = v4;
            } else if (col < N) {
                float bv = BIAS ? bias[col] : 0.f;
                #pragma unroll
                for (int j2 = 0; j2 < 4; ++j2) {
                    float v = acc[m][n][j2] + bv;
                    if (RES) v += b2f(res[(size_t)(row + j2) * N + col]);
                    if (RELU) v = fmaxf(v, 0.f);
                    if (OF32) outf[(size_t)(row + j2) * N + col] = v;
                    if (OBF16) outb[(size_t)(row + j2) * N + col] = f2b(v);
                }
            }
        }
    }
}

// ---------------- wo-GEMM fused with residual-add + LayerNorm epilogue ----------------
// Tile: 16 rows x 512 cols (FULL residual row) per block -> LN computable in-kernel.
// 512 blocks, 4 waves (each owns 128 cols), LDS 66.5KB -> 2 blocks/CU.
// Epilogue: v = acc + bo + x (fp32, in regs) -> write x=f2b(v); cross-lane + cross-wave
// row reduce (sum, sumsq) -> mean/rstd; write h = f2b((v-mean)*rstd*g + b).
__global__ __launch_bounds__(256, 2) void gemmWoLN_kernel(const u16* __restrict__ A,
                                                          const u16* __restrict__ BT,
                                                          const float* __restrict__ bias,
                                                          const float* __restrict__ g,
                                                          const float* __restrict__ lb,
                                                          u16* __restrict__ x,
                                                          u16* __restrict__ h) {
    __shared__ u16 As[16 * 64];
    __shared__ u16 Bs[512 * 64];
    __shared__ float Ps[4][2][16];
    int tid = threadIdx.x;
    int wave = tid >> 6, lane = tid & 63;
    int lr = lane & 15, lg = lane >> 4;
    int m0 = blockIdx.x * 16;
    int srow = lane >> 3;
    int scol = (lane & 7) * 8;
    f32x4 acc[8] = {};
    for (int k0 = 0; k0 < 512; k0 += 64) {
        #pragma unroll
        for (int i = 0; i < 16; ++i) {
            int chunk = wave * 16 + i;                 // 0..63 -> B rows chunk*8..+7
            GLOAD_LDS16(BT + (size_t)(chunk * 8 + srow) * 512 + k0 + scol, &Bs[chunk * 512]);
        }
        if (wave == 0) {
            #pragma unroll
            for (int a = 0; a < 2; ++a)
                GLOAD_LDS16(A + (size_t)(m0 + a * 8 + srow) * 512 + k0 + scol, &As[a * 512]);
        }
        __syncthreads();
        #pragma unroll
        for (int kk = 0; kk < 2; ++kk) {
            bf16x8 af = *(const bf16x8*)(As + lr * 64 + kk * 32 + lg * 8);
            #pragma unroll
            for (int n = 0; n < 8; ++n) {
                bf16x8 bfr = *(const bf16x8*)(Bs + (wave * 128 + n * 16 + lr) * 64 + kk * 32 + lg * 8);
                acc[n] = __builtin_amdgcn_mfma_f32_16x16x32_bf16(af, bfr, acc[n], 0, 0, 0);
            }
        }
        __syncthreads();
    }
    // epilogue
    float v[8][4];
    float s[4] = {0.f, 0.f, 0.f, 0.f}, sq[4] = {0.f, 0.f, 0.f, 0.f};
    #pragma unroll
    for (int n = 0; n < 8; ++n) {
        int col = wave * 128 + n * 16 + lr;
        float bv = bias[col];
        #pragma unroll
        for (int j = 0; j < 4; ++j) {
            int row = m0 + lg * 4 + j;
            float t = acc[n][j] + bv + b2f(x[(size_t)row * Dsz + col]);
            v[n][j] = t;
            x[(size_t)row * Dsz + col] = f2b(t);
            s[j] += t; sq[j] += t * t;
        }
    }
    #pragma unroll
    for (int j = 0; j < 4; ++j) {
        #pragma unroll
        for (int o = 8; o; o >>= 1) { s[j] += __shfl_xor(s[j], o); sq[j] += __shfl_xor(sq[j], o); }
    }
    if (lr == 0) {
        #pragma unroll
        for (int j = 0; j < 4; ++j) {
            Ps[wave][0][lg * 4 + j] = s[j];
            Ps[wave][1][lg * 4 + j] = sq[j];
        }
    }
    __syncthreads();
    #pragma unroll
    for (int j = 0; j < 4; ++j) {
        int rloc = lg * 4 + j;
        float ts = Ps[0][0][rloc] + Ps[1][0][rloc] + Ps[2][0][rloc] + Ps[3][0][rloc];
        float tq = Ps[0][1][rloc] + Ps[1][1][rloc] + Ps[2][1][rloc] + Ps[3][1][rloc];
        float mean = ts * (1.f / 512.f);
        float var = tq * (1.f / 512.f) - mean * mean;
        float rstd = rsqrtf(var + 1e-5f);
        int row = m0 + rloc;
        #pragma unroll
        for (int n = 0; n < 8; ++n) {
            int col = wave * 128 + n * 16 + lr;
            h[(size_t)row * Dsz + col] = f2b((v[n][j] - mean) * rstd * g[col] + lb[col]);
        }
    }
}

// ---------------- flash attention v6: CU-balanced chunk pairing + exp2-folded softmax ----------------
__global__ __launch_bounds__(256, 2) void flash6_kernel(const u16* __restrict__ qkv,
                                                        const u16* __restrict__ vT,
                                                        u16* __restrict__ o) {
    __shared__ u16 Ks[2][64 * 64];
    __shared__ u16 Vs[2][64 * 64];
    int blk = blockIdx.x;
    int bh = blk & 31;
    int idx = blk >> 5;
    int c = (idx < 8) ? (15 - idx) : (idx - 8);   // slot-complement pairing: work/CU = 34 rounds
    int b = bh >> 3, hh = bh & 7;
    int tid = threadIdx.x, wave = tid >> 6, lane = tid & 63;
    int l31 = lane & 31, h5 = lane >> 5;
    int g = c * 4 + wave;
    int qg = g * 32 + l31;
    int ext = (g >> 1) + 1;
    int nt = 2 * c + 2;
    const float k2 = 0.06375871867f;   // (1/sqrt(512)) * log2(e)

    bf16x8 qf[4];
    {
        const u16* qrow = qkv + (size_t)(b * Ssz + qg) * 1536 + hh * 64;
        #pragma unroll
        for (int cb = 0; cb < 4; ++cb)
            qf[cb] = *(const bf16x8*)(qrow + cb * 16 + h5 * 8);
    }
    f32x16 Oa0 = {}, Oa1 = {};
    float m_run = -1e30f, l_run = 0.f;
    int sr = tid >> 3;
    int sc2 = (tid & 7) * 8;
    const u16* kbase = qkv + (size_t)(b * Ssz) * 1536 + 512 + hh * 64;
    const u16* vbase = vT + (size_t)bh * 64 * Ssz;
    int byteA = (sr * 128 + sc2 * 2) ^ ((sr & 7) << 4);
    int byteB = ((sr + 32) * 128 + sc2 * 2) ^ ((sr & 7) << 4);

    {
        bf16x8 kA = *(const bf16x8*)(kbase + (size_t)sr * 1536 + sc2);
        bf16x8 kB = *(const bf16x8*)(kbase + (size_t)(32 + sr) * 1536 + sc2);
        bf16x8 vA = *(const bf16x8*)(vbase + (size_t)sr * Ssz + sc2);
        bf16x8 vB = *(const bf16x8*)(vbase + (size_t)(32 + sr) * Ssz + sc2);
        *(bf16x8*)((char*)Ks[0] + byteA) = kA;
        *(bf16x8*)((char*)Ks[0] + byteB) = kB;
        *(bf16x8*)((char*)Vs[0] + byteA) = vA;
        *(bf16x8*)((char*)Vs[0] + byteB) = vB;
    }
    __syncthreads();

    for (int kt = 0; kt < nt; ++kt) {
        int cur = kt & 1;
        bool pf = (kt + 1 < nt);
        bf16x8 kA, kB, vA, vB;
        if (pf) {
            kA = *(const bf16x8*)(kbase + (size_t)((kt + 1) * 64 + sr) * 1536 + sc2);
            kB = *(const bf16x8*)(kbase + (size_t)((kt + 1) * 64 + 32 + sr) * 1536 + sc2);
            vA = *(const bf16x8*)(vbase + (size_t)sr * Ssz + (kt + 1) * 64 + sc2);
            vB = *(const bf16x8*)(vbase + (size_t)(32 + sr) * Ssz + (kt + 1) * 64 + sc2);
        }
        const u16* Kc = Ks[cur];
        const u16* Vc = Vs[cur];
        if (kt < ext) {
            bool dtile = (kt == ext - 1);
            int mts = (dtile && !(g & 1)) ? 1 : 2;
            f32x16 st[2] = {};
            __builtin_amdgcn_s_setprio(1);
            #pragma unroll
            for (int mt = 0; mt < 2; ++mt)
                if (mt < mts) {
                    int r = mt * 32 + l31;
                    #pragma unroll
                    for (int cb = 0; cb < 4; ++cb) {
                        int byte = (r * 128 + (cb * 16 + h5 * 8) * 2) ^ ((r & 7) << 4);
                        bf16x8 kf = *(const bf16x8*)((char*)Kc + byte);
                        st[mt] = __builtin_amdgcn_mfma_f32_32x32x16_bf16(kf, qf[cb], st[mt], 0, 0, 0);
                    }
                }
            __builtin_amdgcn_s_setprio(0);
            float pmax = -1e30f;
            #pragma unroll
            for (int mt = 0; mt < 2; ++mt)
                if (mt < mts)
                    #pragma unroll
                    for (int r = 0; r < 16; ++r) {
                        float v = st[mt][r];
                        if (dtile) {
                            int kglob = kt * 64 + mt * 32 + (r & 3) + 8 * (r >> 2) + 4 * h5;
                            if (kglob > qg) v = -1e30f;
                        }
                        st[mt][r] = v;
                        pmax = fmaxf(pmax, v);
                    }
            pmax = fmaxf(pmax, __shfl_xor(pmax, 32));
            if (!__all(pmax - m_run <= 181.019336f)) {
                float mn = fmaxf(m_run, pmax);
                float al = exp2f((m_run - mn) * k2);
                l_run *= al;
                #pragma unroll
                for (int r = 0; r < 16; ++r) {
                    int qloc = (r & 3) + 8 * (r >> 2) + 4 * h5;
                    float alr = __shfl(al, qloc);
                    Oa0[r] *= alr; Oa1[r] *= alr;
                }
                m_run = mn;
            }
            float mk = m_run * k2;
            float ls = 0.f;
            u32 pk[2][8];
            #pragma unroll
            for (int mt = 0; mt < 2; ++mt)
                if (mt < mts)
                    #pragma unroll
                    for (int w = 0; w < 8; ++w) {
                        float p0 = exp2f(fmaf(st[mt][2 * w],     k2, -mk));
                        float p1 = exp2f(fmaf(st[mt][2 * w + 1], k2, -mk));
                        ls += p0 + p1;
                        pk[mt][w] = (u32)f2b(p0) | ((u32)f2b(p1) << 16);
                    }
            l_run += ls + __shfl_xor(ls, 32);
            __builtin_amdgcn_s_setprio(1);
            #pragma unroll
            for (int mt = 0; mt < 2; ++mt)
                if (mt < mts) {
                    u32 pko[8];
                    #pragma unroll
                    for (int w = 0; w < 8; ++w)
                        pko[w] = __shfl_xor(pk[mt][w], 32);
                    #pragma unroll
                    for (int kbl = 0; kbl < 2; ++kbl) {
                        int kb = mt * 2 + kbl;
                        u32x4 aw;
                        #pragma unroll
                        for (int w = 0; w < 4; ++w) {
                            int widx = 4 * kbl + 2 * h5 + (w & 1);
                            bool own = (w < 2) != (h5 == 1);
                            aw[w] = own ? pk[mt][widx] : pko[widx];
                        }
                        bf16x8 af = __builtin_bit_cast(bf16x8, aw);
                        #pragma unroll
                        for (int dt = 0; dt < 2; ++dt) {
                            int r = dt * 32 + l31;
                            int byte = (r * 128 + (kb * 16 + h5 * 8) * 2) ^ ((r & 7) << 4);
                            bf16x8 vf = *(const bf16x8*)((char*)Vc + byte);
                            if (dt == 0) Oa0 = __builtin_amdgcn_mfma_f32_32x32x16_bf16(af, vf, Oa0, 0, 0, 0);
                            else         Oa1 = __builtin_amdgcn_mfma_f32_32x32x16_bf16(af, vf, Oa1, 0, 0, 0);
                        }
                    }
                }
            __builtin_amdgcn_s_setprio(0);
        }
        if (pf) {
            u16* Kn = Ks[cur ^ 1];
            u16* Vn = Vs[cur ^ 1];
            *(bf16x8*)((char*)Kn + byteA) = kA;
            *(bf16x8*)((char*)Kn + byteB) = kB;
            *(bf16x8*)((char*)Vn + byteA) = vA;
            *(bf16x8*)((char*)Vn + byteB) = vB;
        }
        __syncthreads();
    }
    float rln = 1.f / l_run;
    u16* obase = o + (size_t)(b * Ssz) * Dsz + hh * 64;
    #pragma unroll
    for (int r = 0; r < 16; ++r) {
        int qloc = (r & 3) + 8 * (r >> 2) + 4 * h5;
        float s = __shfl(rln, qloc);
        u16* orow = obase + (size_t)(g * 32 + qloc) * Dsz + l31;
        orow[0]  = f2b(Oa0[r] * s);
        orow[32] = f2b(Oa1[r] * s);
    }
}

// ---------------- host ----------------
extern "C" void kernel_launch(void* const* d_in, const int* in_sizes, int n_in,
                              void* d_out, int out_size, void* d_ws, size_t ws_size,
                              hipStream_t stream) {
    (void)in_sizes; (void)n_in; (void)out_size; (void)ws_size;
    const int*   tokens = (const int*)d_in[0];
    const float* embed  = (const float*)d_in[1];
    const float* wq     = (const float*)d_in[2];
    const float* wk     = (const float*)d_in[3];
    const float* wv     = (const float*)d_in[4];
    const float* wo     = (const float*)d_in[5];
    const float* bo     = (const float*)d_in[6];
    const float* w1     = (const float*)d_in[7];
    const float* b1     = (const float*)d_in[8];
    const float* w2     = (const float*)d_in[9];
    const float* b2     = (const float*)d_in[10];
    const float* ln_g   = (const float*)d_in[11];
    const float* ln_b   = (const float*)d_in[12];
    const float* lnf_g  = (const float*)d_in[13];
    const float* lnf_b  = (const float*)d_in[14];
    const float* w_out  = (const float*)d_in[15];
    const float* b_out  = (const float*)d_in[16];
    float* out = (float*)d_out;

    char* ws = (char*)d_ws;
    size_t off = 0;
    auto alloc = [&](size_t bytes) {
        void* p = ws + off;
        off += (bytes + 255) & ~(size_t)255;
        return p;
    };
    u16*   x     = (u16*)alloc((size_t)Msz * Dsz * 2);
    u16*   h     = (u16*)alloc((size_t)Msz * Dsz * 2);
    u16*   qkv   = (u16*)alloc((size_t)Msz * 1536 * 2);
    u16*   vT    = (u16*)alloc((size_t)Bsz * Hsz * 64 * Ssz * 2);
    u16*   ob    = (u16*)alloc((size_t)Msz * Dsz * 2);
    u16*   ffh   = (u16*)alloc((size_t)Msz * FFsz * 2);
    u16*   wqkvT = (u16*)alloc((size_t)Lsz * 3 * Dsz * Dsz * 2);
    u16*   woT   = (u16*)alloc((size_t)Lsz * Dsz * Dsz * 2);
    u16*   w1T   = (u16*)alloc((size_t)Lsz * FFsz * Dsz * 2);
    u16*   w2T   = (u16*)alloc((size_t)Lsz * Dsz * FFsz * 2);
    u16*   w_outT= (u16*)alloc((size_t)VszPad * Dsz * 2);

    dim3 tb(256);
    size_t dd = (size_t)Dsz * Dsz;
    // zero the logits-weight pad rows (rows 8000..8191) so OOB-free staging
    hipMemsetAsync(w_outT + (size_t)Vsz * Dsz, 0, (size_t)(VszPad - Vsz) * Dsz * 2, stream);
    tconvw4_kernel<<<dim3(16, 16, Lsz * 4), tb, 0, stream>>>(wq, wk, wv, wo, wqkvT, woT);
    tconv_kernel<<<dim3(64, 16, Lsz), tb, 0, stream>>>(w1, w1T, Dsz, FFsz, (size_t)Dsz * FFsz, (size_t)FFsz * Dsz);
    tconv_kernel<<<dim3(16, 64, Lsz), tb, 0, stream>>>(w2, w2T, FFsz, Dsz, (size_t)FFsz * Dsz, (size_t)Dsz * FFsz);
    tconv_kernel<<<dim3(250, 16, 1), tb, 0, stream>>>(w_out, w_outT, Dsz, Vsz, 0, 0);

    embed_kernel<<<Msz * 256 / 256, tb, 0, stream>>>(tokens, embed, x);

    for (int l = 0; l < Lsz; ++l) {
        ln_kernel<<<Msz / 4, tb, 0, stream>>>(x, ln_g + l * Dsz, ln_b + l * Dsz, h);
        // qkv: 128^2 tile, M-stripe map; Q/K -> qkv buffer, V -> vT transposed (fused)
        gemm_kernel<false, false, false, false, true, false, 4, true><<<dim3(12, Msz / 128), tb, 0, stream>>>(
            h, wqkvT + (size_t)l * 3 * dd, nullptr, nullptr, nullptr, qkv, vT, Msz, 1536, Dsz);
        flash6_kernel<<<dim3(512), tb, 0, stream>>>(qkv, vT, ob);
        // wo + residual + LN fused (replaces wo-GEMM and the second ln dispatch)
        gemmWoLN_kernel<<<dim3(Msz / 16), tb, 0, stream>>>(
            ob, woT + (size_t)l * dd, bo + l * Dsz, ln_g + l * Dsz, ln_b + l * Dsz, x, h);
        gemm_kernel<true, false, true, false, true, false, 4, false><<<dim3(16, Msz / 128), tb, 0, stream>>>(
            h, w1T + (size_t)l * FFsz * Dsz, b1 + l * FFsz, nullptr, nullptr, ffh, nullptr, Msz, FFsz, Dsz);
        gemm_kernel<true, true, false, false, true, false, 2, false><<<dim3(4, Msz / 64), tb, 0, stream>>>(
            ffh, w2T + (size_t)l * Dsz * FFsz, b2 + l * Dsz, x, nullptr, x, nullptr, Msz, Dsz, FFsz);
    }
    ln_kernel<<<Msz / 4, tb, 0, stream>>>(x, lnf_g, lnf_b, h);
    gemm_kernel<true, false, false, true, false, true, 4, false><<<dim3(64, Msz / 128), tb, 0, stream>>>(
        h, w_outT, b_out, nullptr, out, nullptr, nullptr, Msz, Vsz, Dsz);
}

// Round 17
// 1480.721 us; speedup vs baseline: 1.1187x; 1.0014x over previous
//
#include <hip/hip_runtime.h>

#define Bsz 4
#define Ssz 2048
#define Dsz 512
#define Hsz 8
#define Lsz 6
#define Vsz 8000
#define FFsz 2048
#define Msz (Bsz*Ssz)
#define VszPad 8192

typedef unsigned short u16;
typedef unsigned int u32;
typedef __attribute__((ext_vector_type(8))) short bf16x8;
typedef __attribute__((ext_vector_type(4))) float f32x4;
typedef __attribute__((ext_vector_type(16))) float f32x16;
typedef __attribute__((ext_vector_type(4))) u32 u32x4;
typedef __attribute__((ext_vector_type(4))) u16 u16x4;

__device__ __forceinline__ u16 f2b(float f) {
    union { float f; unsigned u; } x; x.f = f;
    return (u16)((x.u + 0x7fffu + ((x.u >> 16) & 1u)) >> 16);
}
__device__ __forceinline__ float b2f(u16 v) {
    union { u32 u; float f; } x; x.u = ((u32)v) << 16; return x.f;
}

#define GLOAD_LDS16(g, l) __builtin_amdgcn_global_load_lds( \
    (const __attribute__((address_space(1))) u32*)(g), \
    (__attribute__((address_space(3))) u32*)(l), 16, 0, 0)

// ---------------- embedding + positional encoding + layer-0 LayerNorm (fused) ----------------
// 1 block per row (256 thr, 2 cols/thr). Writes x = bf16(v) and h = bf16(LN0(v)); LN stats on fp32 v.
__global__ __launch_bounds__(256) void embedln_kernel(const int* __restrict__ tokens,
                                                      const float* __restrict__ embed,
                                                      const float* __restrict__ g,
                                                      const float* __restrict__ bta,
                                                      u16* __restrict__ x,
                                                      u16* __restrict__ h) {
    __shared__ float red[2][4];
    int row = blockIdx.x;
    int p = threadIdx.x;               // pair index 0..255 (cols 2p, 2p+1)
    int tok = tokens[row];
    int s = row & (Ssz - 1);
    float div = __expf((float)p * (-9.210340371976184f / 256.f));
    float ang = (float)s * div;
    float2 e = ((const float2*)(embed + (size_t)tok * Dsz))[p];
    float v0 = e.x + sinf(ang), v1 = e.y + cosf(ang);
    ((u32*)(x + (size_t)row * Dsz))[p] = (u32)f2b(v0) | ((u32)f2b(v1) << 16);
    // row LayerNorm
    float s1 = v0 + v1, s2 = v0 * v0 + v1 * v1;
    #pragma unroll
    for (int o = 32; o; o >>= 1) { s1 += __shfl_xor(s1, o); s2 += __shfl_xor(s2, o); }
    int wave = p >> 6;
    if ((p & 63) == 0) { red[0][wave] = s1; red[1][wave] = s2; }
    __syncthreads();
    float ts = red[0][0] + red[0][1] + red[0][2] + red[0][3];
    float tq = red[1][0] + red[1][1] + red[1][2] + red[1][3];
    float mean = ts * (1.f / 512.f);
    float rstd = rsqrtf(tq * (1.f / 512.f) - mean * mean + 1e-5f);
    int c0 = p * 2;
    u32 ho = (u32)f2b((v0 - mean) * rstd * g[c0] + bta[c0])
           | ((u32)f2b((v1 - mean) * rstd * g[c0 + 1] + bta[c0 + 1]) << 16);
    ((u32*)(h + (size_t)row * Dsz))[p] = ho;
}

// ---------------- layernorm (bf16 in -> bf16 out), 1 wave per row ----------------
__global__ __launch_bounds__(256) void ln_kernel(const u16* __restrict__ x,
                                                 const float* __restrict__ g,
                                                 const float* __restrict__ bta,
                                                 u16* __restrict__ out) {
    int wave = threadIdx.x >> 6, lane = threadIdx.x & 63;
    int row = blockIdx.x * 4 + wave;
    bf16x8 a = ((const bf16x8*)(x + (size_t)row * Dsz))[lane];
    float vals[8];
    #pragma unroll
    for (int i = 0; i < 8; ++i) vals[i] = b2f((u16)a[i]);
    float s = 0.f;
    #pragma unroll
    for (int i = 0; i < 8; ++i) s += vals[i];
    #pragma unroll
    for (int o = 32; o; o >>= 1) s += __shfl_xor(s, o);
    float mean = s * (1.f / 512.f);
    float sq = 0.f;
    #pragma unroll
    for (int i = 0; i < 8; ++i) { float d = vals[i] - mean; sq += d * d; }
    #pragma unroll
    for (int o = 32; o; o >>= 1) sq += __shfl_xor(sq, o);
    float rstd = rsqrtf(sq * (1.f / 512.f) + 1e-5f);
    int base = lane * 8;
    bf16x8 rv;
    #pragma unroll
    for (int i = 0; i < 8; ++i)
        rv[i] = (short)f2b((vals[i] - mean) * rstd * g[base + i] + bta[base + i]);
    *(bf16x8*)(out + (size_t)row * Dsz + base) = rv;
}

// ---------------- tiled transpose + fp32->bf16 convert: src[R,C] -> dst[C,R] ----------------
__global__ __launch_bounds__(256) void tconv_kernel(const float* __restrict__ src,
                                                    u16* __restrict__ dst,
                                                    int R, int C,
                                                    size_t sstride, size_t dstride) {
    __shared__ float tile[32][33];
    const float* s = src + blockIdx.z * sstride;
    u16* d = dst + blockIdx.z * dstride;
    int c0 = blockIdx.x * 32, r0 = blockIdx.y * 32;
    int tx = threadIdx.x & 31, ty = threadIdx.x >> 5;
    #pragma unroll
    for (int i = 0; i < 32; i += 8)
        tile[ty + i][tx] = s[(size_t)(r0 + ty + i) * C + c0 + tx];
    __syncthreads();
    #pragma unroll
    for (int i = 0; i < 32; i += 8)
        d[(size_t)(c0 + ty + i) * R + r0 + tx] = f2b(tile[tx][ty + i]);
}

// ---------------- merged wq/wk/wv/wo transpose (4L z-slices in one launch) ----------------
__global__ __launch_bounds__(256) void tconvw4_kernel(const float* __restrict__ wq,
                                                      const float* __restrict__ wk,
                                                      const float* __restrict__ wv,
                                                      const float* __restrict__ wo,
                                                      u16* __restrict__ qkvT,
                                                      u16* __restrict__ woT) {
    __shared__ float tile[32][33];
    int z = blockIdx.z, which = z / Lsz, l = z % Lsz;
    const float* s = (which == 0 ? wq : which == 1 ? wk : which == 2 ? wv : wo)
                     + (size_t)l * Dsz * Dsz;
    u16* d = (which < 3) ? (qkvT + ((size_t)l * 3 + which) * Dsz * Dsz)
                         : (woT + (size_t)l * Dsz * Dsz);
    int c0 = blockIdx.x * 32, r0 = blockIdx.y * 32;
    int tx = threadIdx.x & 31, ty = threadIdx.x >> 5;
    #pragma unroll
    for (int i = 0; i < 32; i += 8)
        tile[ty + i][tx] = s[(size_t)(r0 + ty + i) * Dsz + c0 + tx];
    __syncthreads();
    #pragma unroll
    for (int i = 0; i < 32; i += 8)
        d[(size_t)(c0 + ty + i) * Dsz + r0 + tx] = f2b(tile[tx][ty + i]);
}

// ---------------- bf16 MFMA GEMM (m97 structure + XCD working-set ordering + BMF tile) ----------------
template<bool BIAS, bool RES, bool RELU, bool OF32, bool OBF16, bool XN, int BMF, bool QKV>
__global__ __launch_bounds__(256, 4) void gemm_kernel(const u16* __restrict__ A,
                                                   const u16* __restrict__ BT,
                                                   const float* __restrict__ bias,
                                                   const u16* __restrict__ res,
                                                   float* __restrict__ outf,
                                                   u16* __restrict__ outb,
                                                   u16* __restrict__ vT,
                                                   int M, int N, int K) {
    __shared__ u16 As[BMF * 32 * 64];
    __shared__ u16 Bs[128 * 64];
    int tid = threadIdx.x;
    int wave = tid >> 6, lane = tid & 63;
    int wm = wave >> 1, wn = wave & 1;
    int gx = gridDim.x;
    int bid = blockIdx.y * gx + blockIdx.x;
    int xcd = bid & 7, j = bid >> 3;
    int mblk, nblk;
    if (XN) { mblk = j >> 3; nblk = xcd * 8 + (j & 7); }       // gx must be 64
    else    { int sm = gridDim.y >> 3; mblk = xcd * sm + j / gx; nblk = j % gx; }
    int m0 = mblk * (BMF * 32), n0 = nblk * 128;
    int lr = lane & 15, lg = lane >> 4;
    int srow = lane >> 3;
    int scol = (lane & 7) * 8;
    f32x4 acc[BMF][4] = {};
    for (int k0 = 0; k0 < K; k0 += 64) {
        #pragma unroll
        for (int i = 0; i < BMF; ++i) {
            int chunk = wave * BMF + i;
            int r = chunk * 8 + srow;
            GLOAD_LDS16(A + (size_t)(m0 + r) * K + k0 + scol, &As[chunk * 512]);
        }
        #pragma unroll
        for (int i = 0; i < 4; ++i) {
            int chunk = wave * 4 + i;
            int r = chunk * 8 + srow;
            GLOAD_LDS16(BT + (size_t)(n0 + r) * K + k0 + scol, &Bs[chunk * 512]);
        }
        __syncthreads();
        #pragma unroll
        for (int kk = 0; kk < 2; ++kk) {
            bf16x8 af[BMF], bfr[4];
            #pragma unroll
            for (int m = 0; m < BMF; ++m)
                af[m] = *(const bf16x8*)(As + (wm * (BMF * 16) + m * 16 + lr) * 64 + kk * 32 + lg * 8);
            #pragma unroll
            for (int n = 0; n < 4; ++n)
                bfr[n] = *(const bf16x8*)(Bs + (wn * 64 + n * 16 + lr) * 64 + kk * 32 + lg * 8);
            #pragma unroll
            for (int m = 0; m < BMF; ++m)
                #pragma unroll
                for (int n = 0; n < 4; ++n)
                    acc[m][n] = __builtin_amdgcn_mfma_f32_16x16x32_bf16(af[m], bfr[n], acc[m][n], 0, 0, 0);
        }
        __syncthreads();
    }
    #pragma unroll
    for (int m = 0; m < BMF; ++m) {
        int row = m0 + wm * (BMF * 16) + m * 16 + lg * 4;
        #pragma unroll
        for (int n = 0; n < 4; ++n) {
            int col = n0 + wn * 64 + n * 16 + lr;
            if (QKV && col >= 1024) {
                int hd = col - 1024;
                int hh = hd >> 6; hd &= 63;
                int b = row >> 11, s = row & 2047;
                u16x4 v4;
                #pragma unroll
                for (int j2 = 0; j2 < 4; ++j2) v4[j2] = f2b(acc[m][n][j2]);
                *(u16x4*)(vT + ((size_t)(b * 8 + hh) * 64 + hd) * Ssz + s) = v4;
            } else if (col < N) {
                float bv = BIAS ? bias[col] : 0.f;
                #pragma unroll
                for (int j2 = 0; j2 < 4; ++j2) {
                    float v = acc[m][n][j2] + bv;
                    if (RES) v += b2f(res[(size_t)(row + j2) * N + col]);
                    if (RELU) v = fmaxf(v, 0.f);
                    if (OF32) outf[(size_t)(row + j2) * N + col] = v;
                    if (OBF16) outb[(size_t)(row + j2) * N + col] = f2b(v);
                }
            }
        }
    }
}

// ---------------- wo-GEMM fused with residual-add + LayerNorm epilogue ----------------
__global__ __launch_bounds__(256, 2) void gemmWoLN_kernel(const u16* __restrict__ A,
                                                          const u16* __restrict__ BT,
                                                          const float* __restrict__ bias,
                                                          const float* __restrict__ g,
                                                          const float* __restrict__ lb,
                                                          u16* __restrict__ x,
                                                          u16* __restrict__ h) {
    __shared__ u16 As[16 * 64];
    __shared__ u16 Bs[512 * 64];
    __shared__ float Ps[4][2][16];
    int tid = threadIdx.x;
    int wave = tid >> 6, lane = tid & 63;
    int lr = lane & 15, lg = lane >> 4;
    int m0 = blockIdx.x * 16;
    int srow = lane >> 3;
    int scol = (lane & 7) * 8;
    f32x4 acc[8] = {};
    for (int k0 = 0; k0 < 512; k0 += 64) {
        #pragma unroll
        for (int i = 0; i < 16; ++i) {
            int chunk = wave * 16 + i;
            GLOAD_LDS16(BT + (size_t)(chunk * 8 + srow) * 512 + k0 + scol, &Bs[chunk * 512]);
        }
        if (wave == 0) {
            #pragma unroll
            for (int a = 0; a < 2; ++a)
                GLOAD_LDS16(A + (size_t)(m0 + a * 8 + srow) * 512 + k0 + scol, &As[a * 512]);
        }
        __syncthreads();
        #pragma unroll
        for (int kk = 0; kk < 2; ++kk) {
            bf16x8 af = *(const bf16x8*)(As + lr * 64 + kk * 32 + lg * 8);
            #pragma unroll
            for (int n = 0; n < 8; ++n) {
                bf16x8 bfr = *(const bf16x8*)(Bs + (wave * 128 + n * 16 + lr) * 64 + kk * 32 + lg * 8);
                acc[n] = __builtin_amdgcn_mfma_f32_16x16x32_bf16(af, bfr, acc[n], 0, 0, 0);
            }
        }
        __syncthreads();
    }
    float v[8][4];
    float s[4] = {0.f, 0.f, 0.f, 0.f}, sq[4] = {0.f, 0.f, 0.f, 0.f};
    #pragma unroll
    for (int n = 0; n < 8; ++n) {
        int col = wave * 128 + n * 16 + lr;
        float bv = bias[col];
        #pragma unroll
        for (int j = 0; j < 4; ++j) {
            int row = m0 + lg * 4 + j;
            float t = acc[n][j] + bv + b2f(x[(size_t)row * Dsz + col]);
            v[n][j] = t;
            x[(size_t)row * Dsz + col] = f2b(t);
            s[j] += t; sq[j] += t * t;
        }
    }
    #pragma unroll
    for (int j = 0; j < 4; ++j) {
        #pragma unroll
        for (int o = 8; o; o >>= 1) { s[j] += __shfl_xor(s[j], o); sq[j] += __shfl_xor(sq[j], o); }
    }
    if (lr == 0) {
        #pragma unroll
        for (int j = 0; j < 4; ++j) {
            Ps[wave][0][lg * 4 + j] = s[j];
            Ps[wave][1][lg * 4 + j] = sq[j];
        }
    }
    __syncthreads();
    #pragma unroll
    for (int j = 0; j < 4; ++j) {
        int rloc = lg * 4 + j;
        float ts = Ps[0][0][rloc] + Ps[1][0][rloc] + Ps[2][0][rloc] + Ps[3][0][rloc];
        float tq = Ps[0][1][rloc] + Ps[1][1][rloc] + Ps[2][1][rloc] + Ps[3][1][rloc];
        float mean = ts * (1.f / 512.f);
        float var = tq * (1.f / 512.f) - mean * mean;
        float rstd = rsqrtf(var + 1e-5f);
        int row = m0 + rloc;
        #pragma unroll
        for (int n = 0; n < 8; ++n) {
            int col = wave * 128 + n * 16 + lr;
            h[(size_t)row * Dsz + col] = f2b((v[n][j] - mean) * rstd * g[col] + lb[col]);
        }
    }
}

// ---------------- flash attention v6: CU-balanced chunk pairing + exp2-folded softmax ----------------
__global__ __launch_bounds__(256, 2) void flash6_kernel(const u16* __restrict__ qkv,
                                                        const u16* __restrict__ vT,
                                                        u16* __restrict__ o) {
    __shared__ u16 Ks[2][64 * 64];
    __shared__ u16 Vs[2][64 * 64];
    int blk = blockIdx.x;
    int bh = blk & 31;
    int idx = blk >> 5;
    int c = (idx < 8) ? (15 - idx) : (idx - 8);   // slot-complement pairing: work/CU = 34 rounds
    int b = bh >> 3, hh = bh & 7;
    int tid = threadIdx.x, wave = tid >> 6, lane = tid & 63;
    int l31 = lane & 31, h5 = lane >> 5;
    int g = c * 4 + wave;
    int qg = g * 32 + l31;
    int ext = (g >> 1) + 1;
    int nt = 2 * c + 2;
    const float k2 = 0.06375871867f;   // (1/sqrt(512)) * log2(e)

    bf16x8 qf[4];
    {
        const u16* qrow = qkv + (size_t)(b * Ssz + qg) * 1536 + hh * 64;
        #pragma unroll
        for (int cb = 0; cb < 4; ++cb)
            qf[cb] = *(const bf16x8*)(qrow + cb * 16 + h5 * 8);
    }
    f32x16 Oa0 = {}, Oa1 = {};
    float m_run = -1e30f, l_run = 0.f;
    int sr = tid >> 3;
    int sc2 = (tid & 7) * 8;
    const u16* kbase = qkv + (size_t)(b * Ssz) * 1536 + 512 + hh * 64;
    const u16* vbase = vT + (size_t)bh * 64 * Ssz;
    int byteA = (sr * 128 + sc2 * 2) ^ ((sr & 7) << 4);
    int byteB = ((sr + 32) * 128 + sc2 * 2) ^ ((sr & 7) << 4);

    {
        bf16x8 kA = *(const bf16x8*)(kbase + (size_t)sr * 1536 + sc2);
        bf16x8 kB = *(const bf16x8*)(kbase + (size_t)(32 + sr) * 1536 + sc2);
        bf16x8 vA = *(const bf16x8*)(vbase + (size_t)sr * Ssz + sc2);
        bf16x8 vB = *(const bf16x8*)(vbase + (size_t)(32 + sr) * Ssz + sc2);
        *(bf16x8*)((char*)Ks[0] + byteA) = kA;
        *(bf16x8*)((char*)Ks[0] + byteB) = kB;
        *(bf16x8*)((char*)Vs[0] + byteA) = vA;
        *(bf16x8*)((char*)Vs[0] + byteB) = vB;
    }
    __syncthreads();

    for (int kt = 0; kt < nt; ++kt) {
        int cur = kt & 1;
        bool pf = (kt + 1 < nt);
        bf16x8 kA, kB, vA, vB;
        if (pf) {
            kA = *(const bf16x8*)(kbase + (size_t)((kt + 1) * 64 + sr) * 1536 + sc2);
            kB = *(const bf16x8*)(kbase + (size_t)((kt + 1) * 64 + 32 + sr) * 1536 + sc2);
            vA = *(const bf16x8*)(vbase + (size_t)sr * Ssz + (kt + 1) * 64 + sc2);
            vB = *(const bf16x8*)(vbase + (size_t)(32 + sr) * Ssz + (kt + 1) * 64 + sc2);
        }
        const u16* Kc = Ks[cur];
        const u16* Vc = Vs[cur];
        if (kt < ext) {
            bool dtile = (kt == ext - 1);
            int mts = (dtile && !(g & 1)) ? 1 : 2;
            f32x16 st[2] = {};
            __builtin_amdgcn_s_setprio(1);
            #pragma unroll
            for (int mt = 0; mt < 2; ++mt)
                if (mt < mts) {
                    int r = mt * 32 + l31;
                    #pragma unroll
                    for (int cb = 0; cb < 4; ++cb) {
                        int byte = (r * 128 + (cb * 16 + h5 * 8) * 2) ^ ((r & 7) << 4);
                        bf16x8 kf = *(const bf16x8*)((char*)Kc + byte);
                        st[mt] = __builtin_amdgcn_mfma_f32_32x32x16_bf16(kf, qf[cb], st[mt], 0, 0, 0);
                    }
                }
            __builtin_amdgcn_s_setprio(0);
            float pmax = -1e30f;
            #pragma unroll
            for (int mt = 0; mt < 2; ++mt)
                if (mt < mts)
                    #pragma unroll
                    for (int r = 0; r < 16; ++r) {
                        float v = st[mt][r];
                        if (dtile) {
                            int kglob = kt * 64 + mt * 32 + (r & 3) + 8 * (r >> 2) + 4 * h5;
                            if (kglob > qg) v = -1e30f;
                        }
                        st[mt][r] = v;
                        pmax = fmaxf(pmax, v);
                    }
            pmax = fmaxf(pmax, __shfl_xor(pmax, 32));
            if (!__all(pmax - m_run <= 181.019336f)) {
                float mn = fmaxf(m_run, pmax);
                float al = exp2f((m_run - mn) * k2);
                l_run *= al;
                #pragma unroll
                for (int r = 0; r < 16; ++r) {
                    int qloc = (r & 3) + 8 * (r >> 2) + 4 * h5;
                    float alr = __shfl(al, qloc);
                    Oa0[r] *= alr; Oa1[r] *= alr;
                }
                m_run = mn;
            }
            float mk = m_run * k2;
            float ls = 0.f;
            u32 pk[2][8];
            #pragma unroll
            for (int mt = 0; mt < 2; ++mt)
                if (mt < mts)
                    #pragma unroll
                    for (int w = 0; w < 8; ++w) {
                        float p0 = exp2f(fmaf(st[mt][2 * w],     k2, -mk));
                        float p1 = exp2f(fmaf(st[mt][2 * w + 1], k2, -mk));
                        ls += p0 + p1;
                        pk[mt][w] = (u32)f2b(p0) | ((u32)f2b(p1) << 16);
                    }
            l_run += ls + __shfl_xor(ls, 32);
            __builtin_amdgcn_s_setprio(1);
            #pragma unroll
            for (int mt = 0; mt < 2; ++mt)
                if (mt < mts) {
                    u32 pko[8];
                    #pragma unroll
                    for (int w = 0; w < 8; ++w)
                        pko[w] = __shfl_xor(pk[mt][w], 32);
                    #pragma unroll
                    for (int kbl = 0; kbl < 2; ++kbl) {
                        int kb = mt * 2 + kbl;
                        u32x4 aw;
                        #pragma unroll
                        for (int w = 0; w < 4; ++w) {
                            int widx = 4 * kbl + 2 * h5 + (w & 1);
                            bool own = (w < 2) != (h5 == 1);
                            aw[w] = own ? pk[mt][widx] : pko[widx];
                        }
                        bf16x8 af = __builtin_bit_cast(bf16x8, aw);
                        #pragma unroll
                        for (int dt = 0; dt < 2; ++dt) {
                            int r = dt * 32 + l31;
                            int byte = (r * 128 + (kb * 16 + h5 * 8) * 2) ^ ((r & 7) << 4);
                            bf16x8 vf = *(const bf16x8*)((char*)Vc + byte);
                            if (dt == 0) Oa0 = __builtin_amdgcn_mfma_f32_32x32x16_bf16(af, vf, Oa0, 0, 0, 0);
                            else         Oa1 = __builtin_amdgcn_mfma_f32_32x32x16_bf16(af, vf, Oa1, 0, 0, 0);
                        }
                    }
                }
            __builtin_amdgcn_s_setprio(0);
        }
        if (pf) {
            u16* Kn = Ks[cur ^ 1];
            u16* Vn = Vs[cur ^ 1];
            *(bf16x8*)((char*)Kn + byteA) = kA;
            *(bf16x8*)((char*)Kn + byteB) = kB;
            *(bf16x8*)((char*)Vn + byteA) = vA;
            *(bf16x8*)((char*)Vn + byteB) = vB;
        }
        __syncthreads();
    }
    float rln = 1.f / l_run;
    u16* obase = o + (size_t)(b * Ssz) * Dsz + hh * 64;
    #pragma unroll
    for (int r = 0; r < 16; ++r) {
        int qloc = (r & 3) + 8 * (r >> 2) + 4 * h5;
        float s = __shfl(rln, qloc);
        u16* orow = obase + (size_t)(g * 32 + qloc) * Dsz + l31;
        orow[0]  = f2b(Oa0[r] * s);
        orow[32] = f2b(Oa1[r] * s);
    }
}

// ---------------- host ----------------
extern "C" void kernel_launch(void* const* d_in, const int* in_sizes, int n_in,
                              void* d_out, int out_size, void* d_ws, size_t ws_size,
                              hipStream_t stream) {
    (void)in_sizes; (void)n_in; (void)out_size; (void)ws_size;
    const int*   tokens = (const int*)d_in[0];
    const float* embed  = (const float*)d_in[1];
    const float* wq     = (const float*)d_in[2];
    const float* wk     = (const float*)d_in[3];
    const float* wv     = (const float*)d_in[4];
    const float* wo     = (const float*)d_in[5];
    const float* bo     = (const float*)d_in[6];
    const float* w1     = (const float*)d_in[7];
    const float* b1     = (const float*)d_in[8];
    const float* w2     = (const float*)d_in[9];
    const float* b2     = (const float*)d_in[10];
    const float* ln_g   = (const float*)d_in[11];
    const float* ln_b   = (const float*)d_in[12];
    const float* lnf_g  = (const float*)d_in[13];
    const float* lnf_b  = (const float*)d_in[14];
    const float* w_out  = (const float*)d_in[15];
    const float* b_out  = (const float*)d_in[16];
    float* out = (float*)d_out;

    char* ws = (char*)d_ws;
    size_t off = 0;
    auto alloc = [&](size_t bytes) {
        void* p = ws + off;
        off += (bytes + 255) & ~(size_t)255;
        return p;
    };
    u16*   x     = (u16*)alloc((size_t)Msz * Dsz * 2);
    u16*   h     = (u16*)alloc((size_t)Msz * Dsz * 2);
    u16*   qkv   = (u16*)alloc((size_t)Msz * 1536 * 2);
    u16*   vT    = (u16*)alloc((size_t)Bsz * Hsz * 64 * Ssz * 2);
    u16*   ob    = (u16*)alloc((size_t)Msz * Dsz * 2);
    u16*   ffh   = (u16*)alloc((size_t)Msz * FFsz * 2);
    u16*   wqkvT = (u16*)alloc((size_t)Lsz * 3 * Dsz * Dsz * 2);
    u16*   woT   = (u16*)alloc((size_t)Lsz * Dsz * Dsz * 2);
    u16*   w1T   = (u16*)alloc((size_t)Lsz * FFsz * Dsz * 2);
    u16*   w2T   = (u16*)alloc((size_t)Lsz * Dsz * FFsz * 2);
    u16*   w_outT= (u16*)alloc((size_t)VszPad * Dsz * 2);

    dim3 tb(256);
    size_t dd = (size_t)Dsz * Dsz;
    // zero the logits-weight pad rows (rows 8000..8191) so OOB-free staging
    hipMemsetAsync(w_outT + (size_t)Vsz * Dsz, 0, (size_t)(VszPad - Vsz) * Dsz * 2, stream);
    tconvw4_kernel<<<dim3(16, 16, Lsz * 4), tb, 0, stream>>>(wq, wk, wv, wo, wqkvT, woT);
    tconv_kernel<<<dim3(64, 16, Lsz), tb, 0, stream>>>(w1, w1T, Dsz, FFsz, (size_t)Dsz * FFsz, (size_t)FFsz * Dsz);
    tconv_kernel<<<dim3(16, 64, Lsz), tb, 0, stream>>>(w2, w2T, FFsz, Dsz, (size_t)FFsz * Dsz, (size_t)Dsz * FFsz);
    tconv_kernel<<<dim3(250, 16, 1), tb, 0, stream>>>(w_out, w_outT, Dsz, Vsz, 0, 0);

    // embed + positional + layer-0 LN fused: writes x and h = LN0(x)
    embedln_kernel<<<dim3(Msz), tb, 0, stream>>>(tokens, embed, ln_g, ln_b, x, h);

    for (int l = 0; l < Lsz; ++l) {
        // qkv: 128^2 tile, M-stripe map; Q/K -> qkv buffer, V -> vT transposed (fused)
        gemm_kernel<false, false, false, false, true, false, 4, true><<<dim3(12, Msz / 128), tb, 0, stream>>>(
            h, wqkvT + (size_t)l * 3 * dd, nullptr, nullptr, nullptr, qkv, vT, Msz, 1536, Dsz);
        flash6_kernel<<<dim3(512), tb, 0, stream>>>(qkv, vT, ob);
        // wo + residual + LN (layer-l params) fused -> x, h (for ffn)
        gemmWoLN_kernel<<<dim3(Msz / 16), tb, 0, stream>>>(
            ob, woT + (size_t)l * dd, bo + l * Dsz, ln_g + l * Dsz, ln_b + l * Dsz, x, h);
        gemm_kernel<true, false, true, false, true, false, 4, false><<<dim3(16, Msz / 128), tb, 0, stream>>>(
            h, w1T + (size_t)l * FFsz * Dsz, b1 + l * FFsz, nullptr, nullptr, ffh, nullptr, Msz, FFsz, Dsz);
        gemm_kernel<true, true, false, false, true, false, 2, false><<<dim3(4, Msz / 64), tb, 0, stream>>>(
            ffh, w2T + (size_t)l * Dsz * FFsz, b2 + l * Dsz, x, nullptr, x, nullptr, Msz, Dsz, FFsz);
        // prepare h for the next stage: layer-(l+1) LN, or final LN after the last layer
        if (l + 1 < Lsz)
            ln_kernel<<<Msz / 4, tb, 0, stream>>>(x, ln_g + (l + 1) * Dsz, ln_b + (l + 1) * Dsz, h);
        else
            ln_kernel<<<Msz / 4, tb, 0, stream>>>(x, lnf_g, lnf_b, h);
    }
    gemm_kernel<true, false, false, true, false, true, 4, false><<<dim3(64, Msz / 128), tb, 0, stream>>>(
        h, w_outT, b_out, nullptr, out, nullptr, nullptr, Msz, Vsz, Dsz);
}